// Round 5
// baseline (399.309 us; speedup 1.0000x reference)
//
#include <hip/hip_runtime.h>

// Problem dims (fixed by the reference)
#define BB 8
#define SS 4096
#define TT 512
#define DD 1024

typedef __attribute__((ext_vector_type(8))) short bf16x8;   // 8 bf16 = 16B
typedef __attribute__((ext_vector_type(4))) short bf16x4;   // 4 bf16 = 8B
typedef __attribute__((ext_vector_type(4))) float f32x4;

// async global->LDS, 16B per lane; LDS dest = wave-uniform base + lane*16
#define GLOAD_LDS16(gp, lp)                                            \
  __builtin_amdgcn_global_load_lds(                                    \
      (const __attribute__((address_space(1))) void*)(gp),             \
      (__attribute__((address_space(3))) void*)(lp), 16, 0, 0)

__device__ inline unsigned short f2bf(float f) {
  unsigned int u = __float_as_uint(f);
  u += 0x7FFFu + ((u >> 16) & 1u);   // round-to-nearest-even
  return (unsigned short)(u >> 16);
}
// pack 16 consecutive f32 -> two bf16x8 (16B-aligned dst)
__device__ inline void pack16(const float* __restrict__ src, short* __restrict__ dst) {
  f32x4 f0 = *(const f32x4*)(src + 0);
  f32x4 f1 = *(const f32x4*)(src + 4);
  f32x4 f2 = *(const f32x4*)(src + 8);
  f32x4 f3 = *(const f32x4*)(src + 12);
  bf16x8 b0, b1;
  b0[0] = (short)f2bf(f0.x); b0[1] = (short)f2bf(f0.y);
  b0[2] = (short)f2bf(f0.z); b0[3] = (short)f2bf(f0.w);
  b0[4] = (short)f2bf(f1.x); b0[5] = (short)f2bf(f1.y);
  b0[6] = (short)f2bf(f1.z); b0[7] = (short)f2bf(f1.w);
  b1[0] = (short)f2bf(f2.x); b1[1] = (short)f2bf(f2.y);
  b1[2] = (short)f2bf(f2.z); b1[3] = (short)f2bf(f2.w);
  b1[4] = (short)f2bf(f3.x); b1[5] = (short)f2bf(f3.y);
  b1[6] = (short)f2bf(f3.z); b1[7] = (short)f2bf(f3.w);
  *(bf16x8*)(dst + 0) = b0;
  *(bf16x8*)(dst + 8) = b1;
}

// ===========================================================================
// FAST PATH (needs 168 MB workspace)
// ws: q_bf16 [T,D] 8MB | c_bf16 [S,D] 64MB | cT_bf16 [D,S] 64MB | p_bf16 32MB
// After qk_kernel_f, the qb+cb region [0, 72MB) is dead; pv split-K partials
// (2 x 16.78MB = 33.5MB, f32) are written there and summed by reduce_kernel.
// ===========================================================================
#define WS_NEED ((size_t)168 << 20)
#define OFF_QB  ((size_t)0)
#define OFF_CB  ((size_t)8 << 20)
#define OFF_CT  ((size_t)72 << 20)
#define OFF_PB  ((size_t)136 << 20)
#define OFF_PART ((size_t)0)        // overlaps qb+cb (dead after qk)

// --- prep: query f32 -> bf16 ------------------------------------------------
__global__ __launch_bounds__(256) void prep_q_kernel(const float* __restrict__ q,
                                                     short* __restrict__ qb) {
  const size_t idx = ((size_t)blockIdx.x * 256 + threadIdx.x) * 16;
  pack16(q + idx, qb + idx);
}

// --- prep: ctx f32 -> c_bf16 [S,D] AND cT_bf16 [D,S] (128s x 64d tiles) -----
// f32 LDS [128][64] with chunk-XOR swizzle: row s stores its d-chunk c (4 f32)
// at slot c ^ (s>>3).  Bank math:
//  phase-1 ds_write_b128 (16 lanes, same s): banks 4*((c^A)&15)+m -> 2-way (free)
//  phase-2 ds_read_b32 (lane a=l&15 reads s=8a+j, fixed d): slot=(d>>2)^a ->
//    banks 4*(((d>>2)^a)&7)+(d&3) -> bijection over 8 groups x2 -> 2-way (free)
// 8 preloaded f32x4/thread (ILP); reads 256B/row, ct writes 256B/row.
__global__ __launch_bounds__(256) void prep_c_kernel(const float* __restrict__ c,
                                                     short* __restrict__ cb,
                                                     short* __restrict__ ct) {
  const int b  = blockIdx.z;
  const int s0 = blockIdx.y * 128;
  const int d0 = blockIdx.x * 64;
  const float* C = c + (size_t)b * SS * DD;
  __shared__ float T[128 * 64];

  const int tid = threadIdx.x;
  const int r0 = tid >> 4;          // s row base 0..15
  const int cc = tid & 15;          // d chunk 0..15

  f32x4 v[8];
#pragma unroll
  for (int i = 0; i < 8; ++i)
    v[i] = *(const f32x4*)(C + (size_t)(s0 + r0 + i * 16) * DD + d0 + cc * 4);

#pragma unroll
  for (int i = 0; i < 8; ++i) {
    const int r = r0 + i * 16;
    bf16x4 o;
    o[0] = (short)f2bf(v[i].x); o[1] = (short)f2bf(v[i].y);
    o[2] = (short)f2bf(v[i].z); o[3] = (short)f2bf(v[i].w);
    *(bf16x4*)(cb + (size_t)b * SS * DD + (size_t)(s0 + r) * DD + d0 + cc * 4) = o;
    *(f32x4*)&T[r * 64 + ((cc ^ (r >> 3)) & 15) * 4] = v[i];
  }
  __syncthreads();

  const int sc  = (tid & 15) * 8;   // s base 0..120
  const int dr0 = tid >> 4;         // d row base 0..15
#pragma unroll
  for (int i = 0; i < 4; ++i) {
    const int d = dr0 + i * 16;     // 0..63
    bf16x8 o;
#pragma unroll
    for (int j = 0; j < 8; ++j) {
      const int s = sc + j;
      o[j] = (short)f2bf(T[s * 64 + (((d >> 2) ^ (s >> 3)) & 15) * 4 + (d & 3)]);
    }
    *(bf16x8*)(ct + (size_t)b * DD * SS + (size_t)(d0 + d) * SS + s0 + sc) = o;
  }
}

// ---------------------------------------------------------------------------
// Shared GEMM core (qk / pv): 128x128 tile, BK=64, double-buffered LDS
// (2 x [128][64] per operand = 64KB), T3 minimum-2-phase schedule:
//   STAGE(next) issued BEFORE ds_read+MFMA(cur); ONE __syncthreads per K-step
//   (its vmcnt(0) drain retires the async stage). Stage latency hides under
//   32 MFMA + cross-block overlap (2 blocks/CU).
// Chunk swizzle (rule #21): lane l stages global chunk ck=(l&7)^(l>>3); read
// slot = (kk*4+quad)^(l16&7) -> 2-way LDS (free).
// No XCD swizzle: working sets L3-resident (m160; confirmed R1 vs R3).
// ---------------------------------------------------------------------------

// --- qk (bf16 NT GEMM, dbuf async staging) + fused mask -> f32 scores -------
__global__ __launch_bounds__(256) void qk_kernel_f(const short* __restrict__ qb,
                                                   const short* __restrict__ cb,
                                                   const int* __restrict__ mask,
                                                   float* __restrict__ p) {
  const int b  = blockIdx.z;
  const int m0 = blockIdx.y * 128;   // T
  const int n0 = blockIdx.x * 128;   // S
  const short* A  = qb + (size_t)b * TT * DD;
  const short* Bt = cb + (size_t)b * SS * DD;

  __shared__ alignas(16) short As[2][128 * 64];
  __shared__ alignas(16) short Bs[2][128 * 64];

  const int tid  = threadIdx.x;
  const int wave = tid >> 6, lane = tid & 63;
  const int quad = lane >> 4, l16 = lane & 15;
  const int wm = (wave >> 1) * 64, wn = (wave & 1) * 64;

  const int rl = lane >> 3;                       // staging row 0..7
  const int ck = (lane & 7) ^ (lane >> 3);        // swizzled k-chunk 0..7
  const int x7 = l16 & 7;                         // read-side row&7

  f32x4 acc[4][4];
#pragma unroll
  for (int i = 0; i < 4; ++i)
#pragma unroll
    for (int j = 0; j < 4; ++j) acc[i][j] = (f32x4){0.f, 0.f, 0.f, 0.f};

#define QK_STAGE(buf, k0)                                                     \
  {                                                                           \
    _Pragma("unroll")                                                         \
    for (int t = 0; t < 4; ++t) {                                             \
      const int rb = wave * 32 + t * 8;                                       \
      GLOAD_LDS16(A  + (size_t)(m0 + rb + rl) * DD + (k0) + ck * 8,           \
                  &As[buf][rb * 64]);                                         \
      GLOAD_LDS16(Bt + (size_t)(n0 + rb + rl) * DD + (k0) + ck * 8,           \
                  &Bs[buf][rb * 64]);                                         \
    }                                                                         \
  }

#define QK_COMPUTE(buf)                                                       \
  {                                                                           \
    _Pragma("unroll")                                                         \
    for (int kk = 0; kk < 2; ++kk) {                                          \
      bf16x8 af[4], bfv[4];                                                   \
      _Pragma("unroll")                                                       \
      for (int i = 0; i < 4; ++i)                                             \
        af[i] = *(const bf16x8*)&As[buf][(wm + i * 16 + l16) * 64 +           \
                                        (((kk * 4 + quad) ^ x7) * 8)];        \
      _Pragma("unroll")                                                       \
      for (int j = 0; j < 4; ++j)                                             \
        bfv[j] = *(const bf16x8*)&Bs[buf][(wn + j * 16 + l16) * 64 +          \
                                          (((kk * 4 + quad) ^ x7) * 8)];      \
      _Pragma("unroll")                                                       \
      for (int i = 0; i < 4; ++i)                                             \
        _Pragma("unroll")                                                     \
        for (int j = 0; j < 4; ++j)                                           \
          acc[i][j] = __builtin_amdgcn_mfma_f32_16x16x32_bf16(                \
              af[i], bfv[j], acc[i][j], 0, 0, 0);                             \
    }                                                                         \
  }

  QK_STAGE(0, 0);
  __syncthreads();
  int cur = 0;
  for (int k0 = 64; k0 < DD; k0 += 64) {
    QK_STAGE(cur ^ 1, k0);
    QK_COMPUTE(cur);
    __syncthreads();
    cur ^= 1;
  }
  QK_COMPUTE(cur);

  // epilogue: scale + mask (masked cols -> -10000; softmax needs no mask)
  float* P = p + (size_t)b * TT * SS;
  int mk[4];
#pragma unroll
  for (int j = 0; j < 4; ++j) mk[j] = mask[b * SS + n0 + wn + j * 16 + l16];
#pragma unroll
  for (int i = 0; i < 4; ++i)
#pragma unroll
    for (int j = 0; j < 4; ++j)
#pragma unroll
      for (int r = 0; r < 4; ++r) {
        const int row = m0 + wm + i * 16 + quad * 4 + r;
        const int col = n0 + wn + j * 16 + l16;
        const float val = (mk[j] == 0) ? -10000.0f : acc[i][j][r] * 0.03125f;
        P[(size_t)row * SS + col] = val;
      }
}

// --- softmax: wave-per-row, zero barriers, zero LDS -------------------------
__global__ __launch_bounds__(256) void softmax_kernel_f(float* __restrict__ p,
                                                        short* __restrict__ pb) {
  const int wave = threadIdx.x >> 6, lane = threadIdx.x & 63;
  const int row = blockIdx.x * 4 + wave;        // b*T + t
  float* pr = p + (size_t)row * SS;
  short* pbr = pb + (size_t)row * SS;

  f32x4 v[16];
  float mx = -3.0e38f;
#pragma unroll
  for (int h = 0; h < 16; ++h) {
    v[h] = *(const f32x4*)(pr + h * 256 + lane * 4);
    mx = fmaxf(mx, fmaxf(fmaxf(v[h].x, v[h].y), fmaxf(v[h].z, v[h].w)));
  }
#pragma unroll
  for (int off = 32; off > 0; off >>= 1) mx = fmaxf(mx, __shfl_xor(mx, off));

  float sum = 0.f;
#pragma unroll
  for (int h = 0; h < 16; ++h) {
    v[h].x = __expf(v[h].x - mx);
    v[h].y = __expf(v[h].y - mx);
    v[h].z = __expf(v[h].z - mx);
    v[h].w = __expf(v[h].w - mx);
    sum += (v[h].x + v[h].y) + (v[h].z + v[h].w);
  }
#pragma unroll
  for (int off = 32; off > 0; off >>= 1) sum += __shfl_xor(sum, off);
  const float inv = 1.0f / sum;

#pragma unroll
  for (int h = 0; h < 16; ++h) {
    f32x4 o;
    o.x = v[h].x * inv; o.y = v[h].y * inv;
    o.z = v[h].z * inv; o.w = v[h].w * inv;
    *(f32x4*)(pr + h * 256 + lane * 4) = o;
    bf16x4 ob;
    ob[0] = (short)f2bf(o.x); ob[1] = (short)f2bf(o.y);
    ob[2] = (short)f2bf(o.z); ob[3] = (short)f2bf(o.w);
    *(bf16x4*)(pbr + h * 256 + lane * 4) = ob;
  }
}

// --- pv (bf16 NT GEMM, dbuf async staging, split-K=2, partial stores) -------
__global__ __launch_bounds__(256) void pv_kernel_f(const short* __restrict__ pb,
                                                   const short* __restrict__ ct,
                                                   float* __restrict__ part) {
  const int n0 = blockIdx.x * 128;   // D
  const int m0 = blockIdx.y * 128;   // T
  const int z  = blockIdx.z;
  const int b  = z >> 1;
  const int ks = z & 1;              // K slice: s in [ks*2048, +2048)
  const short* A  = pb + (size_t)b * TT * SS;
  const short* Bt = ct + (size_t)b * DD * SS;

  __shared__ alignas(16) short As[2][128 * 64];
  __shared__ alignas(16) short Bs[2][128 * 64];

  const int tid  = threadIdx.x;
  const int wave = tid >> 6, lane = tid & 63;
  const int quad = lane >> 4, l16 = lane & 15;
  const int wm = (wave >> 1) * 64, wn = (wave & 1) * 64;

  const int rl = lane >> 3;
  const int ck = (lane & 7) ^ (lane >> 3);
  const int x7 = l16 & 7;

  f32x4 acc[4][4];
#pragma unroll
  for (int i = 0; i < 4; ++i)
#pragma unroll
    for (int j = 0; j < 4; ++j) acc[i][j] = (f32x4){0.f, 0.f, 0.f, 0.f};

#define PV_STAGE(buf, k0)                                                     \
  {                                                                           \
    _Pragma("unroll")                                                         \
    for (int t = 0; t < 4; ++t) {                                             \
      const int rb = wave * 32 + t * 8;                                       \
      GLOAD_LDS16(A  + (size_t)(m0 + rb + rl) * SS + (k0) + ck * 8,           \
                  &As[buf][rb * 64]);                                         \
      GLOAD_LDS16(Bt + (size_t)(n0 + rb + rl) * SS + (k0) + ck * 8,           \
                  &Bs[buf][rb * 64]);                                         \
    }                                                                         \
  }

  const int kbeg = ks * 2048;
  const int kend = kbeg + 2048;
  PV_STAGE(0, kbeg);
  __syncthreads();
  int cur = 0;
  for (int k0 = kbeg + 64; k0 < kend; k0 += 64) {
    PV_STAGE(cur ^ 1, k0);
    QK_COMPUTE(cur);          // same fragment/MFMA body (macro reuse)
    __syncthreads();
    cur ^= 1;
  }
  QK_COMPUTE(cur);

  // race-free epilogue: each K-slice owns its own 16.78MB partial buffer
  float* E = part + (size_t)ks * BB * TT * DD + (size_t)b * TT * DD;
#pragma unroll
  for (int i = 0; i < 4; ++i)
#pragma unroll
    for (int j = 0; j < 4; ++j)
#pragma unroll
      for (int r = 0; r < 4; ++r) {
        const int row = m0 + wm + i * 16 + quad * 4 + r;
        const int col = n0 + wn + j * 16 + l16;
        E[(size_t)row * DD + col] = acc[i][j][r];
      }
}

// --- reduce: expected = sum of 2 split-K partials (vectorized) --------------
__global__ __launch_bounds__(256) void reduce_kernel(const float* __restrict__ part,
                                                     float* __restrict__ e) {
  const size_t idx = ((size_t)blockIdx.x * 256 + threadIdx.x) * 4;
  const size_t N = (size_t)BB * TT * DD;
  f32x4 a0 = *(const f32x4*)(part + idx);
  f32x4 a1 = *(const f32x4*)(part + N + idx);
  f32x4 o;
  o.x = a0.x + a1.x;
  o.y = a0.y + a1.y;
  o.z = a0.z + a1.z;
  o.w = a0.w + a1.w;
  *(f32x4*)(e + idx) = o;
}

// ===========================================================================
// FALLBACK PATH (R4 kernels, used when ws_size < WS_NEED)
// ===========================================================================
__global__ __launch_bounds__(256) void qk_kernel(const float* __restrict__ q,
                                                 const float* __restrict__ c,
                                                 float* __restrict__ p) {
  const int b  = blockIdx.z;
  const int m0 = blockIdx.y * 128;
  const int n0 = blockIdx.x * 128;
  const float* A  = q + (size_t)b * TT * DD;
  const float* Bt = c + (size_t)b * SS * DD;
  __shared__ alignas(16) short As[128 * 40];
  __shared__ alignas(16) short Bs[128 * 40];
  const int tid  = threadIdx.x;
  const int wave = tid >> 6, lane = tid & 63;
  const int quad = lane >> 4, l16 = lane & 15;
  const int wm = (wave >> 1) * 64, wn = (wave & 1) * 64;
  f32x4 acc[4][4];
#pragma unroll
  for (int i = 0; i < 4; ++i)
#pragma unroll
    for (int j = 0; j < 4; ++j) acc[i][j] = (f32x4){0.f, 0.f, 0.f, 0.f};
  const int ar = tid >> 1;
  const int ak = (tid & 1) * 16;
  for (int k0 = 0; k0 < DD; k0 += 32) {
    __syncthreads();
    pack16(A  + (size_t)(m0 + ar) * DD + k0 + ak, &As[ar * 40 + ak]);
    pack16(Bt + (size_t)(n0 + ar) * DD + k0 + ak, &Bs[ar * 40 + ak]);
    __syncthreads();
    bf16x8 af[4], bfv[4];
#pragma unroll
  for (int i = 0; i < 4; ++i)
      af[i] = *(const bf16x8*)&As[(wm + i * 16 + l16) * 40 + quad * 8];
#pragma unroll
    for (int j = 0; j < 4; ++j)
      bfv[j] = *(const bf16x8*)&Bs[(wn + j * 16 + l16) * 40 + quad * 8];
#pragma unroll
    for (int i = 0; i < 4; ++i)
#pragma unroll
      for (int j = 0; j < 4; ++j)
        acc[i][j] = __builtin_amdgcn_mfma_f32_16x16x32_bf16(af[i], bfv[j],
                                                            acc[i][j], 0, 0, 0);
  }
  float* P = p + (size_t)b * TT * SS;
#pragma unroll
  for (int i = 0; i < 4; ++i)
#pragma unroll
    for (int j = 0; j < 4; ++j)
#pragma unroll
      for (int r = 0; r < 4; ++r) {
        const int row = m0 + wm + i * 16 + quad * 4 + r;
        const int col = n0 + wn + j * 16 + l16;
        P[(size_t)row * SS + col] = acc[i][j][r] * 0.03125f;
      }
}

__global__ __launch_bounds__(256) void softmax_kernel(float* __restrict__ p,
                                                      const int* __restrict__ mask) {
  const int row = blockIdx.x;
  const int b   = row >> 9;
  float* pr = p + (size_t)row * SS;
  const int* mr = mask + b * SS;
  const int tid = threadIdx.x;
  const int wave = tid >> 6, lane = tid & 63;
  float v[16];
  float mx = -3.0e38f;
#pragma unroll
  for (int h = 0; h < 4; ++h) {
    const int base = tid * 4 + h * 1024;
    f32x4 s = *(const f32x4*)(pr + base);
    const int4 m4 = *(const int4*)(mr + base);
#pragma unroll
    for (int j = 0; j < 4; ++j) {
      float f = (j == 0 ? s.x : j == 1 ? s.y : j == 2 ? s.z : s.w);
      const int mk = (j == 0 ? m4.x : j == 1 ? m4.y : j == 2 ? m4.z : m4.w);
      f = fminf(fmaxf(f, -1.0e30f), 1.0e30f);
      f = (mk == 0) ? -10000.0f : f;
      v[h * 4 + j] = f;
      mx = fmaxf(mx, f);
    }
  }
#pragma unroll
  for (int off = 32; off > 0; off >>= 1) mx = fmaxf(mx, __shfl_down(mx, off));
  __shared__ float red[4];
  if (lane == 0) red[wave] = mx;
  __syncthreads();
  mx = fmaxf(fmaxf(red[0], red[1]), fmaxf(red[2], red[3]));
  __syncthreads();
  float e[16];
  float sum = 0.f;
#pragma unroll
  for (int k = 0; k < 16; ++k) { e[k] = __expf(v[k] - mx); sum += e[k]; }
#pragma unroll
  for (int off = 32; off > 0; off >>= 1) sum += __shfl_down(sum, off);
  if (lane == 0) red[wave] = sum;
  __syncthreads();
  const float inv = 1.0f / (red[0] + red[1] + red[2] + red[3]);
#pragma unroll
  for (int h = 0; h < 4; ++h) {
    const int base = tid * 4 + h * 1024;
    f32x4 o;
    o.x = e[h * 4 + 0] * inv; o.y = e[h * 4 + 1] * inv;
    o.z = e[h * 4 + 2] * inv; o.w = e[h * 4 + 3] * inv;
    *(f32x4*)(pr + base) = o;
  }
}

__global__ __launch_bounds__(256) void pv_kernel(const float* __restrict__ p,
                                                 const float* __restrict__ c,
                                                 float* __restrict__ e) {
  const int b  = blockIdx.z;
  const int m0 = blockIdx.y * 128;
  const int n0 = blockIdx.x * 128;
  const float* A  = p + (size_t)b * TT * SS;
  const float* Bm = c + (size_t)b * SS * DD;
  __shared__ alignas(16) short As[128 * 40];
  __shared__ alignas(16) short Bs[128 * 40];
  const int tid  = threadIdx.x;
  const int wave = tid >> 6, lane = tid & 63;
  const int quad = lane >> 4, l16 = lane & 15;
  const int wm = (wave >> 1) * 64, wn = (wave & 1) * 64;
  f32x4 acc[4][4];
#pragma unroll
  for (int i = 0; i < 4; ++i)
#pragma unroll
    for (int j = 0; j < 4; ++j) acc[i][j] = (f32x4){0.f, 0.f, 0.f, 0.f};
  const int ar = tid >> 1;
  const int ak = (tid & 1) * 16;
  const int kk = tid >> 3;
  const int c0 = (tid & 7) * 16;
  for (int k0 = 0; k0 < SS; k0 += 32) {
    __syncthreads();
    pack16(A + (size_t)(m0 + ar) * SS + k0 + ak, &As[ar * 40 + ak]);
    {
      const float* bp = Bm + (size_t)(k0 + kk) * DD + n0 + c0;
#pragma unroll
      for (int h = 0; h < 4; ++h) {
        f32x4 f = *(const f32x4*)(bp + h * 4);
        Bs[(c0 + h * 4 + 0) * 40 + kk] = (short)f2bf(f.x);
        Bs[(c0 + h * 4 + 1) * 40 + kk] = (short)f2bf(f.y);
        Bs[(c0 + h * 4 + 2) * 40 + kk] = (short)f2bf(f.z);
        Bs[(c0 + h * 4 + 3) * 40 + kk] = (short)f2bf(f.w);
      }
    }
    __syncthreads();
    bf16x8 af[4], bfv[4];
#pragma unroll
    for (int i = 0; i < 4; ++i)
      af[i] = *(const bf16x8*)&As[(wm + i * 16 + l16) * 40 + quad * 8];
#pragma unroll
    for (int j = 0; j < 4; ++j)
      bfv[j] = *(const bf16x8*)&Bs[(wn + j * 16 + l16) * 40 + quad * 8];
#pragma unroll
    for (int i = 0; i < 4; ++i)
#pragma unroll
      for (int j = 0; j < 4; ++j)
        acc[i][j] = __builtin_amdgcn_mfma_f32_16x16x32_bf16(af[i], bfv[j],
                                                            acc[i][j], 0, 0, 0);
  }
  float* E = e + (size_t)b * TT * DD;
#pragma unroll
  for (int i = 0; i < 4; ++i)
#pragma unroll
    for (int j = 0; j < 4; ++j)
#pragma unroll
      for (int r = 0; r < 4; ++r) {
        const int row = m0 + wm + i * 16 + quad * 4 + r;
        const int col = n0 + wn + j * 16 + l16;
        E[(size_t)row * DD + col] = acc[i][j][r];
      }
}

// ---------------------------------------------------------------------------
extern "C" void kernel_launch(void* const* d_in, const int* in_sizes, int n_in,
                              void* d_out, int out_size, void* d_ws, size_t ws_size,
                              hipStream_t stream) {
  const float* ctx   = (const float*)d_in[0];   // [8,4096,1024] f32
  const float* query = (const float*)d_in[1];   // [8,512,1024]  f32
  const int*   mask  = (const int*)d_in[2];     // [8,4096]      int32

  float* expected = (float*)d_out;                              // [8,512,1024] f32
  float* p        = (float*)d_out + (size_t)BB * TT * DD;       // [8,512,4096] f32

  if (ws_size >= WS_NEED) {
    char* ws = (char*)d_ws;
    short* qb = (short*)(ws + OFF_QB);
    short* cb = (short*)(ws + OFF_CB);
    short* ct = (short*)(ws + OFF_CT);
    short* pb = (short*)(ws + OFF_PB);
    float* part = (float*)(ws + OFF_PART);   // reuses qb+cb region (dead after qk)

    prep_q_kernel<<<dim3((BB * TT * DD) / (256 * 16)), 256, 0, stream>>>(query, qb);
    prep_c_kernel<<<dim3(DD / 64, SS / 128, BB), 256, 0, stream>>>(ctx, cb, ct);
    qk_kernel_f<<<dim3(SS / 128, TT / 128, BB), 256, 0, stream>>>(qb, cb, mask, p);
    softmax_kernel_f<<<dim3((BB * TT) / 4), 256, 0, stream>>>(p, pb);
    pv_kernel_f<<<dim3(DD / 128, TT / 128, BB * 2), 256, 0, stream>>>(pb, ct, part);
    reduce_kernel<<<dim3((BB * TT * DD) / (256 * 4)), 256, 0, stream>>>(part, expected);
  } else {
    // fallback: R4 proven path
    qk_kernel<<<dim3(SS / 128, TT / 128, BB), 256, 0, stream>>>(query, ctx, p);
    softmax_kernel<<<dim3(BB * TT), 256, 0, stream>>>(p, mask);
    pv_kernel<<<dim3(DD / 128, TT / 128, BB), 256, 0, stream>>>(p, ctx, expected);
  }
}

// Round 6
// 357.107 us; speedup vs baseline: 1.1182x; 1.1182x over previous
//
#include <hip/hip_runtime.h>

// Problem dims (fixed by the reference)
#define BB 8
#define SS 4096
#define TT 512
#define DD 1024

typedef __attribute__((ext_vector_type(8))) short bf16x8;   // 8 bf16 = 16B
typedef __attribute__((ext_vector_type(4))) short bf16x4;   // 4 bf16 = 8B
typedef __attribute__((ext_vector_type(4))) float f32x4;

// async global->LDS, 16B per lane; LDS dest = wave-uniform base + lane*16
#define GLOAD_LDS16(gp, lp)                                            \
  __builtin_amdgcn_global_load_lds(                                    \
      (const __attribute__((address_space(1))) void*)(gp),             \
      (__attribute__((address_space(3))) void*)(lp), 16, 0, 0)

__device__ inline unsigned short f2bf(float f) {
  unsigned int u = __float_as_uint(f);
  u += 0x7FFFu + ((u >> 16) & 1u);   // round-to-nearest-even
  return (unsigned short)(u >> 16);
}
// pack 16 consecutive f32 -> two bf16x8 (16B-aligned dst)
__device__ inline void pack16(const float* __restrict__ src, short* __restrict__ dst) {
  f32x4 f0 = *(const f32x4*)(src + 0);
  f32x4 f1 = *(const f32x4*)(src + 4);
  f32x4 f2 = *(const f32x4*)(src + 8);
  f32x4 f3 = *(const f32x4*)(src + 12);
  bf16x8 b0, b1;
  b0[0] = (short)f2bf(f0.x); b0[1] = (short)f2bf(f0.y);
  b0[2] = (short)f2bf(f0.z); b0[3] = (short)f2bf(f0.w);
  b0[4] = (short)f2bf(f1.x); b0[5] = (short)f2bf(f1.y);
  b0[6] = (short)f2bf(f1.z); b0[7] = (short)f2bf(f1.w);
  b1[0] = (short)f2bf(f2.x); b1[1] = (short)f2bf(f2.y);
  b1[2] = (short)f2bf(f2.z); b1[3] = (short)f2bf(f2.w);
  b1[4] = (short)f2bf(f3.x); b1[5] = (short)f2bf(f3.y);
  b1[6] = (short)f2bf(f3.z); b1[7] = (short)f2bf(f3.w);
  *(bf16x8*)(dst + 0) = b0;
  *(bf16x8*)(dst + 8) = b1;
}

// ===========================================================================
// FAST PATH (needs 168 MB workspace)
// ws: q_bf16 [T,D] 8MB | c_bf16 [S,D] 64MB | part (2x16.78MB, old ct region)
//     | pb 32MB at 136MB.  NO ct: pv consumes cb directly via
//     ds_read_b64_tr_b16 hardware-transpose reads (T10).
// ===========================================================================
#define WS_NEED ((size_t)168 << 20)
#define OFF_QB  ((size_t)0)
#define OFF_CB  ((size_t)8 << 20)
#define OFF_PART ((size_t)72 << 20)   // old ct region (pv reads cb, so no overlap)
#define OFF_PB  ((size_t)136 << 20)

// --- prep: query f32 -> bf16 ------------------------------------------------
__global__ __launch_bounds__(256) void prep_q_kernel(const float* __restrict__ q,
                                                     short* __restrict__ qb) {
  const size_t idx = ((size_t)blockIdx.x * 256 + threadIdx.x) * 16;
  pack16(q + idx, qb + idx);
}

// --- prep: ctx f32 -> c_bf16 [S,D] (pure streaming, no LDS, no transpose) ---
__global__ __launch_bounds__(256) void prep_cb_kernel(const float* __restrict__ c,
                                                      short* __restrict__ cb) {
  const size_t idx = ((size_t)blockIdx.x * 256 + threadIdx.x) * 16;
  pack16(c + idx, cb + idx);
}

// ---------------------------------------------------------------------------
// GEMM cores: 128x128 tile, BK=64, double-buffered, global_load_lds staging.
// qk: A,B both row-of-K layout (chunk swizzle, b128 reads).
// pv: A (pb) as qk; B (V) staged ROW-MAJOR from cb into subtiled LDS
//     [kg=k>>2][dg=d>>4][k&3][d&15] and consumed via ds_read_b64_tr_b16:
//     per 16-lane group, lane l16 receives column l16, rows 0..3 of one
//     4x16 subtile (one tr-read per 4 k-rows; 2 tr-reads = k-octet frag).
//     Staging source permutation (m173): lane l holds (k=kg*4+((l&7)>>1),
//     d=(l>>3)*16+(l&1)*8 +0..7) -> 4 rows x 256B contiguous segments.
// No XCD swizzle: working sets L3-resident (m160; confirmed R1 vs R3).
// ---------------------------------------------------------------------------

// --- qk (bf16 NT GEMM, dbuf async staging) + fused mask -> f32 scores -------
__global__ __launch_bounds__(256) void qk_kernel_f(const short* __restrict__ qb,
                                                   const short* __restrict__ cb,
                                                   const int* __restrict__ mask,
                                                   float* __restrict__ p) {
  const int b  = blockIdx.z;
  const int m0 = blockIdx.y * 128;   // T
  const int n0 = blockIdx.x * 128;   // S
  const short* A  = qb + (size_t)b * TT * DD;
  const short* Bt = cb + (size_t)b * SS * DD;

  __shared__ alignas(16) short As[2][128 * 64];
  __shared__ alignas(16) short Bs[2][128 * 64];

  const int tid  = threadIdx.x;
  const int wave = tid >> 6, lane = tid & 63;
  const int quad = lane >> 4, l16 = lane & 15;
  const int wm = (wave >> 1) * 64, wn = (wave & 1) * 64;

  const int rl = lane >> 3;                       // staging row 0..7
  const int ck = (lane & 7) ^ (lane >> 3);        // swizzled k-chunk 0..7
  const int x7 = l16 & 7;                         // read-side row&7

  f32x4 acc[4][4];
#pragma unroll
  for (int i = 0; i < 4; ++i)
#pragma unroll
    for (int j = 0; j < 4; ++j) acc[i][j] = (f32x4){0.f, 0.f, 0.f, 0.f};

#define QK_STAGE(buf, k0)                                                     \
  {                                                                           \
    _Pragma("unroll")                                                         \
    for (int t = 0; t < 4; ++t) {                                             \
      const int rb = wave * 32 + t * 8;                                       \
      GLOAD_LDS16(A  + (size_t)(m0 + rb + rl) * DD + (k0) + ck * 8,           \
                  &As[buf][rb * 64]);                                         \
      GLOAD_LDS16(Bt + (size_t)(n0 + rb + rl) * DD + (k0) + ck * 8,           \
                  &Bs[buf][rb * 64]);                                         \
    }                                                                         \
  }

#define QK_COMPUTE(buf)                                                       \
  {                                                                           \
    _Pragma("unroll")                                                         \
    for (int kk = 0; kk < 2; ++kk) {                                          \
      bf16x8 af[4], bfv[4];                                                   \
      _Pragma("unroll")                                                       \
      for (int i = 0; i < 4; ++i)                                             \
        af[i] = *(const bf16x8*)&As[buf][(wm + i * 16 + l16) * 64 +           \
                                        (((kk * 4 + quad) ^ x7) * 8)];        \
      _Pragma("unroll")                                                       \
      for (int j = 0; j < 4; ++j)                                             \
        bfv[j] = *(const bf16x8*)&Bs[buf][(wn + j * 16 + l16) * 64 +          \
                                          (((kk * 4 + quad) ^ x7) * 8)];      \
      _Pragma("unroll")                                                       \
      for (int i = 0; i < 4; ++i)                                             \
        _Pragma("unroll")                                                     \
        for (int j = 0; j < 4; ++j)                                           \
          acc[i][j] = __builtin_amdgcn_mfma_f32_16x16x32_bf16(                \
              af[i], bfv[j], acc[i][j], 0, 0, 0);                             \
    }                                                                         \
  }

  QK_STAGE(0, 0);
  __syncthreads();
  int cur = 0;
  for (int k0 = 64; k0 < DD; k0 += 64) {
    QK_STAGE(cur ^ 1, k0);
    QK_COMPUTE(cur);
    __syncthreads();
    cur ^= 1;
  }
  QK_COMPUTE(cur);

  // epilogue: scale + mask (masked cols -> -10000; softmax needs no mask)
  float* P = p + (size_t)b * TT * SS;
  int mk[4];
#pragma unroll
  for (int j = 0; j < 4; ++j) mk[j] = mask[b * SS + n0 + wn + j * 16 + l16];
#pragma unroll
  for (int i = 0; i < 4; ++i)
#pragma unroll
    for (int j = 0; j < 4; ++j)
#pragma unroll
      for (int r = 0; r < 4; ++r) {
        const int row = m0 + wm + i * 16 + quad * 4 + r;
        const int col = n0 + wn + j * 16 + l16;
        const float val = (mk[j] == 0) ? -10000.0f : acc[i][j][r] * 0.03125f;
        P[(size_t)row * SS + col] = val;
      }
}

// --- softmax: wave-per-row, zero barriers, zero LDS -------------------------
__global__ __launch_bounds__(256) void softmax_kernel_f(float* __restrict__ p,
                                                        short* __restrict__ pb) {
  const int wave = threadIdx.x >> 6, lane = threadIdx.x & 63;
  const int row = blockIdx.x * 4 + wave;        // b*T + t
  float* pr = p + (size_t)row * SS;
  short* pbr = pb + (size_t)row * SS;

  f32x4 v[16];
  float mx = -3.0e38f;
#pragma unroll
  for (int h = 0; h < 16; ++h) {
    v[h] = *(const f32x4*)(pr + h * 256 + lane * 4);
    mx = fmaxf(mx, fmaxf(fmaxf(v[h].x, v[h].y), fmaxf(v[h].z, v[h].w)));
  }
#pragma unroll
  for (int off = 32; off > 0; off >>= 1) mx = fmaxf(mx, __shfl_xor(mx, off));

  float sum = 0.f;
#pragma unroll
  for (int h = 0; h < 16; ++h) {
    v[h].x = __expf(v[h].x - mx);
    v[h].y = __expf(v[h].y - mx);
    v[h].z = __expf(v[h].z - mx);
    v[h].w = __expf(v[h].w - mx);
    sum += (v[h].x + v[h].y) + (v[h].z + v[h].w);
  }
#pragma unroll
  for (int off = 32; off > 0; off >>= 1) sum += __shfl_xor(sum, off);
  const float inv = 1.0f / sum;

#pragma unroll
  for (int h = 0; h < 16; ++h) {
    f32x4 o;
    o.x = v[h].x * inv; o.y = v[h].y * inv;
    o.z = v[h].z * inv; o.w = v[h].w * inv;
    *(f32x4*)(pr + h * 256 + lane * 4) = o;
    bf16x4 ob;
    ob[0] = (short)f2bf(o.x); ob[1] = (short)f2bf(o.y);
    ob[2] = (short)f2bf(o.z); ob[3] = (short)f2bf(o.w);
    *(bf16x4*)(pbr + h * 256 + lane * 4) = ob;
  }
}

// --- pv: A from pb (as qk); B from cb rows via subtiled LDS + tr-reads ------
__global__ __launch_bounds__(256) void pv_kernel_f(const short* __restrict__ pb,
                                                   const short* __restrict__ cb,
                                                   float* __restrict__ part) {
  const int n0 = blockIdx.x * 128;   // D
  const int m0 = blockIdx.y * 128;   // T
  const int z  = blockIdx.z;
  const int b  = z >> 1;
  const int ks = z & 1;              // K slice: s in [ks*2048, +2048)
  const short* A   = pb + (size_t)b * TT * SS;
  const short* Vrm = cb + (size_t)b * SS * DD;   // V row-major [s][d]

  __shared__ alignas(16) short As[2][128 * 64];
  __shared__ alignas(16) short Bs[2][64 * 128];  // subtiled [16][8][4][16]

  const int tid  = threadIdx.x;
  const int wave = tid >> 6, lane = tid & 63;
  const int quad = lane >> 4, l16 = lane & 15;
  const int wm = (wave >> 1) * 64, wn = (wave & 1) * 64;

  const int rl = lane >> 3;                 // A staging row 0..7
  const int ck = (lane & 7) ^ (lane >> 3);  // A swizzled k-chunk
  const int x7 = l16 & 7;

  // B staging source decomposition (dest = linear lane*16 in subtiled layout)
  const int rB  = (lane & 7) >> 1;          // k within rowblock 0..3
  const int dB  = (lane >> 3) * 16 + (lane & 1) * 8;   // d offset 0..120

  // B tr-read per-lane base (bytes into LDS)
  const unsigned ldsB0 = (unsigned)(unsigned long long)&Bs[0][0];
  const unsigned baseBq = ldsB0 + (unsigned)(quad * 2048 + (wave & 1) * 512 + l16 * 8);

  f32x4 acc[4][4];
#pragma unroll
  for (int i = 0; i < 4; ++i)
#pragma unroll
    for (int j = 0; j < 4; ++j) acc[i][j] = (f32x4){0.f, 0.f, 0.f, 0.f};

#define PV_STAGE(buf, k0)                                                     \
  {                                                                           \
    _Pragma("unroll")                                                         \
    for (int t = 0; t < 4; ++t) {                                             \
      const int rb = wave * 32 + t * 8;                                       \
      GLOAD_LDS16(A + (size_t)(m0 + rb + rl) * SS + (k0) + ck * 8,            \
                  &As[buf][rb * 64]);                                         \
      const int kg = wave * 4 + t;          /* rowblock 0..15 */              \
      GLOAD_LDS16(Vrm + (size_t)((k0) + kg * 4 + rB) * DD + n0 + dB,          \
                  &Bs[buf][kg * 512]);                                        \
    }                                                                         \
  }

#define PV_COMPUTE(buf)                                                       \
  {                                                                           \
    const unsigned bb = baseBq + (unsigned)(buf) * 16384u;                    \
    _Pragma("unroll")                                                         \
    for (int kk = 0; kk < 2; ++kk) {                                          \
      bf16x8 af[4];                                                           \
      _Pragma("unroll")                                                       \
      for (int i = 0; i < 4; ++i)                                             \
        af[i] = *(const bf16x8*)&As[buf][(wm + i * 16 + l16) * 64 +           \
                                        (((kk * 4 + quad) ^ x7) * 8)];        \
      union { struct { int2 lo, hi; } p; bf16x8 v; } bu[4];                   \
      _Pragma("unroll")                                                       \
      for (int j = 0; j < 4; ++j) {                                           \
        const unsigned aj = bb + (unsigned)(kk * 8192 + j * 128);             \
        asm volatile("ds_read_b64_tr_b16 %0, %1"                              \
                     : "=v"(bu[j].p.lo) : "v"(aj) : "memory");                \
        asm volatile("ds_read_b64_tr_b16 %0, %1 offset:1024"                  \
                     : "=v"(bu[j].p.hi) : "v"(aj) : "memory");                \
      }                                                                       \
      asm volatile("s_waitcnt lgkmcnt(0)" ::: "memory");                      \
      __builtin_amdgcn_sched_barrier(0);                                      \
      _Pragma("unroll")                                                       \
      for (int i = 0; i < 4; ++i)                                             \
        _Pragma("unroll")                                                     \
        for (int j = 0; j < 4; ++j)                                           \
          acc[i][j] = __builtin_amdgcn_mfma_f32_16x16x32_bf16(                \
              af[i], bu[j].v, acc[i][j], 0, 0, 0);                            \
    }                                                                         \
  }

  const int kbeg = ks * 2048;
  const int kend = kbeg + 2048;
  PV_STAGE(0, kbeg);
  __syncthreads();
  int cur = 0;
  for (int k0 = kbeg + 64; k0 < kend; k0 += 64) {
    PV_STAGE(cur ^ 1, k0);
    PV_COMPUTE(cur);
    __syncthreads();
    cur ^= 1;
  }
  PV_COMPUTE(cur);

  // race-free epilogue: each K-slice owns its own 16.78MB partial buffer
  float* E = part + (size_t)ks * BB * TT * DD + (size_t)b * TT * DD;
#pragma unroll
  for (int i = 0; i < 4; ++i)
#pragma unroll
    for (int j = 0; j < 4; ++j)
#pragma unroll
      for (int r = 0; r < 4; ++r) {
        const int row = m0 + wm + i * 16 + quad * 4 + r;
        const int col = n0 + wn + j * 16 + l16;
        E[(size_t)row * DD + col] = acc[i][j][r];
      }
}

// --- reduce: expected = sum of 2 split-K partials (vectorized) --------------
__global__ __launch_bounds__(256) void reduce_kernel(const float* __restrict__ part,
                                                     float* __restrict__ e) {
  const size_t idx = ((size_t)blockIdx.x * 256 + threadIdx.x) * 4;
  const size_t N = (size_t)BB * TT * DD;
  f32x4 a0 = *(const f32x4*)(part + idx);
  f32x4 a1 = *(const f32x4*)(part + N + idx);
  f32x4 o;
  o.x = a0.x + a1.x;
  o.y = a0.y + a1.y;
  o.z = a0.z + a1.z;
  o.w = a0.w + a1.w;
  *(f32x4*)(e + idx) = o;
}

// ===========================================================================
// FALLBACK PATH (R4 kernels, used when ws_size < WS_NEED)
// ===========================================================================
__global__ __launch_bounds__(256) void qk_kernel(const float* __restrict__ q,
                                                 const float* __restrict__ c,
                                                 float* __restrict__ p) {
  const int b  = blockIdx.z;
  const int m0 = blockIdx.y * 128;
  const int n0 = blockIdx.x * 128;
  const float* A  = q + (size_t)b * TT * DD;
  const float* Bt = c + (size_t)b * SS * DD;
  __shared__ alignas(16) short As[128 * 40];
  __shared__ alignas(16) short Bs[128 * 40];
  const int tid  = threadIdx.x;
  const int wave = tid >> 6, lane = tid & 63;
  const int quad = lane >> 4, l16 = lane & 15;
  const int wm = (wave >> 1) * 64, wn = (wave & 1) * 64;
  f32x4 acc[4][4];
#pragma unroll
  for (int i = 0; i < 4; ++i)
#pragma unroll
    for (int j = 0; j < 4; ++j) acc[i][j] = (f32x4){0.f, 0.f, 0.f, 0.f};
  const int ar = tid >> 1;
  const int ak = (tid & 1) * 16;
  for (int k0 = 0; k0 < DD; k0 += 32) {
    __syncthreads();
    pack16(A  + (size_t)(m0 + ar) * DD + k0 + ak, &As[ar * 40 + ak]);
    pack16(Bt + (size_t)(n0 + ar) * DD + k0 + ak, &Bs[ar * 40 + ak]);
    __syncthreads();
    bf16x8 af[4], bfv[4];
#pragma unroll
  for (int i = 0; i < 4; ++i)
      af[i] = *(const bf16x8*)&As[(wm + i * 16 + l16) * 40 + quad * 8];
#pragma unroll
    for (int j = 0; j < 4; ++j)
      bfv[j] = *(const bf16x8*)&Bs[(wn + j * 16 + l16) * 40 + quad * 8];
#pragma unroll
    for (int i = 0; i < 4; ++i)
#pragma unroll
      for (int j = 0; j < 4; ++j)
        acc[i][j] = __builtin_amdgcn_mfma_f32_16x16x32_bf16(af[i], bfv[j],
                                                            acc[i][j], 0, 0, 0);
  }
  float* P = p + (size_t)b * TT * SS;
#pragma unroll
  for (int i = 0; i < 4; ++i)
#pragma unroll
    for (int j = 0; j < 4; ++j)
#pragma unroll
      for (int r = 0; r < 4; ++r) {
        const int row = m0 + wm + i * 16 + quad * 4 + r;
        const int col = n0 + wn + j * 16 + l16;
        P[(size_t)row * SS + col] = acc[i][j][r] * 0.03125f;
      }
}

__global__ __launch_bounds__(256) void softmax_kernel(float* __restrict__ p,
                                                      const int* __restrict__ mask) {
  const int row = blockIdx.x;
  const int b   = row >> 9;
  float* pr = p + (size_t)row * SS;
  const int* mr = mask + b * SS;
  const int tid = threadIdx.x;
  const int wave = tid >> 6, lane = tid & 63;
  float v[16];
  float mx = -3.0e38f;
#pragma unroll
  for (int h = 0; h < 4; ++h) {
    const int base = tid * 4 + h * 1024;
    f32x4 s = *(const f32x4*)(pr + base);
    const int4 m4 = *(const int4*)(mr + base);
#pragma unroll
    for (int j = 0; j < 4; ++j) {
      float f = (j == 0 ? s.x : j == 1 ? s.y : j == 2 ? s.z : s.w);
      const int mk = (j == 0 ? m4.x : j == 1 ? m4.y : j == 2 ? m4.z : m4.w);
      f = fminf(fmaxf(f, -1.0e30f), 1.0e30f);
      f = (mk == 0) ? -10000.0f : f;
      v[h * 4 + j] = f;
      mx = fmaxf(mx, f);
    }
  }
#pragma unroll
  for (int off = 32; off > 0; off >>= 1) mx = fmaxf(mx, __shfl_down(mx, off));
  __shared__ float red[4];
  if (lane == 0) red[wave] = mx;
  __syncthreads();
  mx = fmaxf(fmaxf(red[0], red[1]), fmaxf(red[2], red[3]));
  __syncthreads();
  float e[16];
  float sum = 0.f;
#pragma unroll
  for (int k = 0; k < 16; ++k) { e[k] = __expf(v[k] - mx); sum += e[k]; }
#pragma unroll
  for (int off = 32; off > 0; off >>= 1) sum += __shfl_down(sum, off);
  if (lane == 0) red[wave] = sum;
  __syncthreads();
  const float inv = 1.0f / (red[0] + red[1] + red[2] + red[3]);
#pragma unroll
  for (int h = 0; h < 4; ++h) {
    const int base = tid * 4 + h * 1024;
    f32x4 o;
    o.x = e[h * 4 + 0] * inv; o.y = e[h * 4 + 1] * inv;
    o.z = e[h * 4 + 2] * inv; o.w = e[h * 4 + 3] * inv;
    *(f32x4*)(pr + base) = o;
  }
}

__global__ __launch_bounds__(256) void pv_kernel(const float* __restrict__ p,
                                                 const float* __restrict__ c,
                                                 float* __restrict__ e) {
  const int b  = blockIdx.z;
  const int m0 = blockIdx.y * 128;
  const int n0 = blockIdx.x * 128;
  const float* A  = p + (size_t)b * TT * SS;
  const float* Bm = c + (size_t)b * SS * DD;
  __shared__ alignas(16) short As[128 * 40];
  __shared__ alignas(16) short Bs[128 * 40];
  const int tid  = threadIdx.x;
  const int wave = tid >> 6, lane = tid & 63;
  const int quad = lane >> 4, l16 = lane & 15;
  const int wm = (wave >> 1) * 64, wn = (wave & 1) * 64;
  f32x4 acc[4][4];
#pragma unroll
  for (int i = 0; i < 4; ++i)
#pragma unroll
    for (int j = 0; j < 4; ++j) acc[i][j] = (f32x4){0.f, 0.f, 0.f, 0.f};
  const int ar = tid >> 1;
  const int ak = (tid & 1) * 16;
  const int kk = tid >> 3;
  const int c0 = (tid & 7) * 16;
  for (int k0 = 0; k0 < SS; k0 += 32) {
    __syncthreads();
    pack16(A + (size_t)(m0 + ar) * SS + k0 + ak, &As[ar * 40 + ak]);
    {
      const float* bp = Bm + (size_t)(k0 + kk) * DD + n0 + c0;
#pragma unroll
      for (int h = 0; h < 4; ++h) {
        f32x4 f = *(const f32x4*)(bp + h * 4);
        Bs[(c0 + h * 4 + 0) * 40 + kk] = (short)f2bf(f.x);
        Bs[(c0 + h * 4 + 1) * 40 + kk] = (short)f2bf(f.y);
        Bs[(c0 + h * 4 + 2) * 40 + kk] = (short)f2bf(f.z);
        Bs[(c0 + h * 4 + 3) * 40 + kk] = (short)f2bf(f.w);
      }
    }
    __syncthreads();
    bf16x8 af[4], bfv[4];
#pragma unroll
    for (int i = 0; i < 4; ++i)
      af[i] = *(const bf16x8*)&As[(wm + i * 16 + l16) * 40 + quad * 8];
#pragma unroll
    for (int j = 0; j < 4; ++j)
      bfv[j] = *(const bf16x8*)&Bs[(wn + j * 16 + l16) * 40 + quad * 8];
#pragma unroll
    for (int i = 0; i < 4; ++i)
#pragma unroll
      for (int j = 0; j < 4; ++j)
        acc[i][j] = __builtin_amdgcn_mfma_f32_16x16x32_bf16(af[i], bfv[j],
                                                            acc[i][j], 0, 0, 0);
  }
  float* E = e + (size_t)b * TT * DD;
#pragma unroll
  for (int i = 0; i < 4; ++i)
#pragma unroll
    for (int j = 0; j < 4; ++j)
#pragma unroll
      for (int r = 0; r < 4; ++r) {
        const int row = m0 + wm + i * 16 + quad * 4 + r;
        const int col = n0 + wn + j * 16 + l16;
        E[(size_t)row * DD + col] = acc[i][j][r];
      }
}

// ---------------------------------------------------------------------------
extern "C" void kernel_launch(void* const* d_in, const int* in_sizes, int n_in,
                              void* d_out, int out_size, void* d_ws, size_t ws_size,
                              hipStream_t stream) {
  const float* ctx   = (const float*)d_in[0];   // [8,4096,1024] f32
  const float* query = (const float*)d_in[1];   // [8,512,1024]  f32
  const int*   mask  = (const int*)d_in[2];     // [8,4096]      int32

  float* expected = (float*)d_out;                              // [8,512,1024] f32
  float* p        = (float*)d_out + (size_t)BB * TT * DD;       // [8,512,4096] f32

  if (ws_size >= WS_NEED) {
    char* ws = (char*)d_ws;
    short* qb = (short*)(ws + OFF_QB);
    short* cb = (short*)(ws + OFF_CB);
    short* pb = (short*)(ws + OFF_PB);
    float* part = (float*)(ws + OFF_PART);

    prep_q_kernel<<<dim3((BB * TT * DD) / (256 * 16)), 256, 0, stream>>>(query, qb);
    prep_cb_kernel<<<dim3((BB * SS * DD) / (256 * 16)), 256, 0, stream>>>(ctx, cb);
    qk_kernel_f<<<dim3(SS / 128, TT / 128, BB), 256, 0, stream>>>(qb, cb, mask, p);
    softmax_kernel_f<<<dim3((BB * TT) / 4), 256, 0, stream>>>(p, pb);
    pv_kernel_f<<<dim3(DD / 128, TT / 128, BB * 2), 256, 0, stream>>>(pb, cb, part);
    reduce_kernel<<<dim3((BB * TT * DD) / (256 * 4)), 256, 0, stream>>>(part, expected);
  } else {
    // fallback: R4 proven path
    qk_kernel<<<dim3(SS / 128, TT / 128, BB), 256, 0, stream>>>(query, ctx, p);
    softmax_kernel<<<dim3(BB * TT), 256, 0, stream>>>(p, mask);
    pv_kernel<<<dim3(DD / 128, TT / 128, BB), 256, 0, stream>>>(p, ctx, expected);
  }
}

// Round 7
// 356.956 us; speedup vs baseline: 1.1186x; 1.0004x over previous
//
#include <hip/hip_runtime.h>

// Problem dims (fixed by the reference)
#define BB 8
#define SS 4096
#define TT 512
#define DD 1024

typedef __attribute__((ext_vector_type(8))) short bf16x8;   // 8 bf16 = 16B
typedef __attribute__((ext_vector_type(4))) short bf16x4;   // 4 bf16 = 8B
typedef __attribute__((ext_vector_type(4))) float f32x4;

// async global->LDS, 16B per lane; LDS dest = wave-uniform base + lane*16
#define GLOAD_LDS16(gp, lp)                                            \
  __builtin_amdgcn_global_load_lds(                                    \
      (const __attribute__((address_space(1))) void*)(gp),             \
      (__attribute__((address_space(3))) void*)(lp), 16, 0, 0)

// T4 counted-vmcnt barrier discipline (m218/m201 pattern)
#define ASM_VMCNT(n) asm volatile("s_waitcnt vmcnt(" #n ")" ::: "memory")
#define BARRIER() __builtin_amdgcn_s_barrier()

__device__ inline unsigned short f2bf(float f) {
  unsigned int u = __float_as_uint(f);
  u += 0x7FFFu + ((u >> 16) & 1u);   // round-to-nearest-even
  return (unsigned short)(u >> 16);
}
// pack 16 consecutive f32 -> two bf16x8 (16B-aligned dst)
__device__ inline void pack16(const float* __restrict__ src, short* __restrict__ dst) {
  f32x4 f0 = *(const f32x4*)(src + 0);
  f32x4 f1 = *(const f32x4*)(src + 4);
  f32x4 f2 = *(const f32x4*)(src + 8);
  f32x4 f3 = *(const f32x4*)(src + 12);
  bf16x8 b0, b1;
  b0[0] = (short)f2bf(f0.x); b0[1] = (short)f2bf(f0.y);
  b0[2] = (short)f2bf(f0.z); b0[3] = (short)f2bf(f0.w);
  b0[4] = (short)f2bf(f1.x); b0[5] = (short)f2bf(f1.y);
  b0[6] = (short)f2bf(f1.z); b0[7] = (short)f2bf(f1.w);
  b1[0] = (short)f2bf(f2.x); b1[1] = (short)f2bf(f2.y);
  b1[2] = (short)f2bf(f2.z); b1[3] = (short)f2bf(f2.w);
  b1[4] = (short)f2bf(f3.x); b1[5] = (short)f2bf(f3.y);
  b1[6] = (short)f2bf(f3.z); b1[7] = (short)f2bf(f3.w);
  *(bf16x8*)(dst + 0) = b0;
  *(bf16x8*)(dst + 8) = b1;
}

// ===========================================================================
// FAST PATH (needs 168 MB workspace)
// ws: q_bf16 [T,D] 8MB | c_bf16 [S,D] 64MB | part (2x16.78MB, old ct region)
//     | pb 32MB at 136MB.  NO ct: pv consumes cb directly via
//     ds_read_b64_tr_b16 hardware-transpose reads (T10).
// ===========================================================================
#define WS_NEED ((size_t)168 << 20)
#define OFF_QB  ((size_t)0)
#define OFF_CB  ((size_t)8 << 20)
#define OFF_PART ((size_t)72 << 20)   // old ct region (pv reads cb, so no overlap)
#define OFF_PB  ((size_t)136 << 20)

// --- prep: query f32 -> bf16 ------------------------------------------------
__global__ __launch_bounds__(256) void prep_q_kernel(const float* __restrict__ q,
                                                     short* __restrict__ qb) {
  const size_t idx = ((size_t)blockIdx.x * 256 + threadIdx.x) * 16;
  pack16(q + idx, qb + idx);
}

// --- prep: ctx f32 -> c_bf16 [S,D] (pure streaming, no LDS, no transpose) ---
__global__ __launch_bounds__(256) void prep_cb_kernel(const float* __restrict__ c,
                                                      short* __restrict__ cb) {
  const size_t idx = ((size_t)blockIdx.x * 256 + threadIdx.x) * 16;
  pack16(c + idx, cb + idx);
}

// ---------------------------------------------------------------------------
// GEMM cores: 128x128 tile, BK=64, double-buffered, global_load_lds staging,
// T4 counted-vmcnt schedule:
//   STAGE(next); vmcnt(8); barrier; COMPUTE(cur); barrier;
// vmcnt(8) retires everything EXCEPT the 8 just-issued loads -> previous
// tile's loads have landed (per-wave FIFO, all waves) while the prefetch
// stays in flight across the barrier. Epilogue drains vmcnt(0) once.
// qk: A,B both row-of-K layout (chunk swizzle, b128 reads).
// pv: A (pb) as qk; B (V) staged ROW-MAJOR from cb into subtiled LDS
//     [kg][dg][k&3][d&15], consumed via ds_read_b64_tr_b16 (T10).
// No XCD swizzle: working sets L3-resident (m160; confirmed R1 vs R3).
// ---------------------------------------------------------------------------

// --- qk (bf16 NT GEMM, dbuf async staging) + fused mask -> f32 scores -------
__global__ __launch_bounds__(256) void qk_kernel_f(const short* __restrict__ qb,
                                                   const short* __restrict__ cb,
                                                   const int* __restrict__ mask,
                                                   float* __restrict__ p) {
  const int b  = blockIdx.z;
  const int m0 = blockIdx.y * 128;   // T
  const int n0 = blockIdx.x * 128;   // S
  const short* A  = qb + (size_t)b * TT * DD;
  const short* Bt = cb + (size_t)b * SS * DD;

  __shared__ alignas(16) short As[2][128 * 64];
  __shared__ alignas(16) short Bs[2][128 * 64];

  const int tid  = threadIdx.x;
  const int wave = tid >> 6, lane = tid & 63;
  const int quad = lane >> 4, l16 = lane & 15;
  const int wm = (wave >> 1) * 64, wn = (wave & 1) * 64;

  const int rl = lane >> 3;                       // staging row 0..7
  const int ck = (lane & 7) ^ (lane >> 3);        // swizzled k-chunk 0..7
  const int x7 = l16 & 7;                         // read-side row&7

  f32x4 acc[4][4];
#pragma unroll
  for (int i = 0; i < 4; ++i)
#pragma unroll
    for (int j = 0; j < 4; ++j) acc[i][j] = (f32x4){0.f, 0.f, 0.f, 0.f};

#define QK_STAGE(buf, k0)                                                     \
  {                                                                           \
    _Pragma("unroll")                                                         \
    for (int t = 0; t < 4; ++t) {                                             \
      const int rb = wave * 32 + t * 8;                                       \
      GLOAD_LDS16(A  + (size_t)(m0 + rb + rl) * DD + (k0) + ck * 8,           \
                  &As[buf][rb * 64]);                                         \
      GLOAD_LDS16(Bt + (size_t)(n0 + rb + rl) * DD + (k0) + ck * 8,           \
                  &Bs[buf][rb * 64]);                                         \
    }                                                                         \
  }

#define QK_COMPUTE(buf)                                                       \
  {                                                                           \
    _Pragma("unroll")                                                         \
    for (int kk = 0; kk < 2; ++kk) {                                          \
      bf16x8 af[4], bfv[4];                                                   \
      _Pragma("unroll")                                                       \
      for (int i = 0; i < 4; ++i)                                             \
        af[i] = *(const bf16x8*)&As[buf][(wm + i * 16 + l16) * 64 +           \
                                        (((kk * 4 + quad) ^ x7) * 8)];        \
      _Pragma("unroll")                                                       \
      for (int j = 0; j < 4; ++j)                                             \
        bfv[j] = *(const bf16x8*)&Bs[buf][(wn + j * 16 + l16) * 64 +          \
                                          (((kk * 4 + quad) ^ x7) * 8)];      \
      _Pragma("unroll")                                                       \
      for (int i = 0; i < 4; ++i)                                             \
        _Pragma("unroll")                                                     \
        for (int j = 0; j < 4; ++j)                                           \
          acc[i][j] = __builtin_amdgcn_mfma_f32_16x16x32_bf16(                \
              af[i], bfv[j], acc[i][j], 0, 0, 0);                             \
    }                                                                         \
  }

  QK_STAGE(0, 0);
  int cur = 0;
  for (int k0 = 64; k0 < DD; k0 += 64) {
    QK_STAGE(cur ^ 1, k0);   // 8 loads in flight for next tile
    ASM_VMCNT(8);            // previous tile's 8 loads retired (all waves)
    BARRIER();
    QK_COMPUTE(cur);
    BARRIER();               // reads done before next iter overwrites buf
    cur ^= 1;
  }
  ASM_VMCNT(0);
  BARRIER();
  QK_COMPUTE(cur);

  // epilogue: scale + mask (masked cols -> -10000; softmax needs no mask)
  float* P = p + (size_t)b * TT * SS;
  int mk[4];
#pragma unroll
  for (int j = 0; j < 4; ++j) mk[j] = mask[b * SS + n0 + wn + j * 16 + l16];
#pragma unroll
  for (int i = 0; i < 4; ++i)
#pragma unroll
    for (int j = 0; j < 4; ++j)
#pragma unroll
      for (int r = 0; r < 4; ++r) {
        const int row = m0 + wm + i * 16 + quad * 4 + r;
        const int col = n0 + wn + j * 16 + l16;
        const float val = (mk[j] == 0) ? -10000.0f : acc[i][j][r] * 0.03125f;
        P[(size_t)row * SS + col] = val;
      }
}

// --- softmax: wave-per-row, zero barriers, zero LDS -------------------------
__global__ __launch_bounds__(256) void softmax_kernel_f(float* __restrict__ p,
                                                        short* __restrict__ pb) {
  const int wave = threadIdx.x >> 6, lane = threadIdx.x & 63;
  const int row = blockIdx.x * 4 + wave;        // b*T + t
  float* pr = p + (size_t)row * SS;
  short* pbr = pb + (size_t)row * SS;

  f32x4 v[16];
  float mx = -3.0e38f;
#pragma unroll
  for (int h = 0; h < 16; ++h) {
    v[h] = *(const f32x4*)(pr + h * 256 + lane * 4);
    mx = fmaxf(mx, fmaxf(fmaxf(v[h].x, v[h].y), fmaxf(v[h].z, v[h].w)));
  }
#pragma unroll
  for (int off = 32; off > 0; off >>= 1) mx = fmaxf(mx, __shfl_xor(mx, off));

  float sum = 0.f;
#pragma unroll
  for (int h = 0; h < 16; ++h) {
    v[h].x = __expf(v[h].x - mx);
    v[h].y = __expf(v[h].y - mx);
    v[h].z = __expf(v[h].z - mx);
    v[h].w = __expf(v[h].w - mx);
    sum += (v[h].x + v[h].y) + (v[h].z + v[h].w);
  }
#pragma unroll
  for (int off = 32; off > 0; off >>= 1) sum += __shfl_xor(sum, off);
  const float inv = 1.0f / sum;

#pragma unroll
  for (int h = 0; h < 16; ++h) {
    f32x4 o;
    o.x = v[h].x * inv; o.y = v[h].y * inv;
    o.z = v[h].z * inv; o.w = v[h].w * inv;
    *(f32x4*)(pr + h * 256 + lane * 4) = o;
    bf16x4 ob;
    ob[0] = (short)f2bf(o.x); ob[1] = (short)f2bf(o.y);
    ob[2] = (short)f2bf(o.z); ob[3] = (short)f2bf(o.w);
    *(bf16x4*)(pbr + h * 256 + lane * 4) = ob;
  }
}

// --- pv: A from pb (as qk); B from cb rows via subtiled LDS + tr-reads ------
__global__ __launch_bounds__(256) void pv_kernel_f(const short* __restrict__ pb,
                                                   const short* __restrict__ cb,
                                                   float* __restrict__ part) {
  const int n0 = blockIdx.x * 128;   // D
  const int m0 = blockIdx.y * 128;   // T
  const int z  = blockIdx.z;
  const int b  = z >> 1;
  const int ks = z & 1;              // K slice: s in [ks*2048, +2048)
  const short* A   = pb + (size_t)b * TT * SS;
  const short* Vrm = cb + (size_t)b * SS * DD;   // V row-major [s][d]

  __shared__ alignas(16) short As[2][128 * 64];
  __shared__ alignas(16) short Bs[2][64 * 128];  // subtiled [16][8][4][16]

  const int tid  = threadIdx.x;
  const int wave = tid >> 6, lane = tid & 63;
  const int quad = lane >> 4, l16 = lane & 15;
  const int wm = (wave >> 1) * 64, wn = (wave & 1) * 64;

  const int rl = lane >> 3;                 // A staging row 0..7
  const int ck = (lane & 7) ^ (lane >> 3);  // A swizzled k-chunk
  const int x7 = l16 & 7;

  // B staging source decomposition (dest = linear lane*16 in subtiled layout)
  const int rB  = (lane & 7) >> 1;          // k within rowblock 0..3
  const int dB  = (lane >> 3) * 16 + (lane & 1) * 8;   // d offset 0..120

  // B tr-read per-lane base (bytes into LDS)
  const unsigned ldsB0 = (unsigned)(unsigned long long)&Bs[0][0];
  const unsigned baseBq = ldsB0 + (unsigned)(quad * 2048 + (wave & 1) * 512 + l16 * 8);

  f32x4 acc[4][4];
#pragma unroll
  for (int i = 0; i < 4; ++i)
#pragma unroll
    for (int j = 0; j < 4; ++j) acc[i][j] = (f32x4){0.f, 0.f, 0.f, 0.f};

#define PV_STAGE(buf, k0)                                                     \
  {                                                                           \
    _Pragma("unroll")                                                         \
    for (int t = 0; t < 4; ++t) {                                             \
      const int rb = wave * 32 + t * 8;                                       \
      GLOAD_LDS16(A + (size_t)(m0 + rb + rl) * SS + (k0) + ck * 8,            \
                  &As[buf][rb * 64]);                                         \
      const int kg = wave * 4 + t;          /* rowblock 0..15 */              \
      GLOAD_LDS16(Vrm + (size_t)((k0) + kg * 4 + rB) * DD + n0 + dB,          \
                  &Bs[buf][kg * 512]);                                        \
    }                                                                         \
  }

#define PV_COMPUTE(buf)                                                       \
  {                                                                           \
    const unsigned bb = baseBq + (unsigned)(buf) * 16384u;                    \
    _Pragma("unroll")                                                         \
    for (int kk = 0; kk < 2; ++kk) {                                          \
      bf16x8 af[4];                                                           \
      _Pragma("unroll")                                                       \
      for (int i = 0; i < 4; ++i)                                             \
        af[i] = *(const bf16x8*)&As[buf][(wm + i * 16 + l16) * 64 +           \
                                        (((kk * 4 + quad) ^ x7) * 8)];        \
      union { struct { int2 lo, hi; } p; bf16x8 v; } bu[4];                   \
      _Pragma("unroll")                                                       \
      for (int j = 0; j < 4; ++j) {                                           \
        const unsigned aj = bb + (unsigned)(kk * 8192 + j * 128);             \
        asm volatile("ds_read_b64_tr_b16 %0, %1"                              \
                     : "=v"(bu[j].p.lo) : "v"(aj) : "memory");                \
        asm volatile("ds_read_b64_tr_b16 %0, %1 offset:1024"                  \
                     : "=v"(bu[j].p.hi) : "v"(aj) : "memory");                \
      }                                                                       \
      asm volatile("s_waitcnt lgkmcnt(0)" ::: "memory");                      \
      __builtin_amdgcn_sched_barrier(0);                                      \
      _Pragma("unroll")                                                       \
      for (int i = 0; i < 4; ++i)                                             \
        _Pragma("unroll")                                                     \
        for (int j = 0; j < 4; ++j)                                           \
          acc[i][j] = __builtin_amdgcn_mfma_f32_16x16x32_bf16(                \
              af[i], bu[j].v, acc[i][j], 0, 0, 0);                            \
    }                                                                         \
  }

  const int kbeg = ks * 2048;
  const int kend = kbeg + 2048;
  PV_STAGE(0, kbeg);
  int cur = 0;
  for (int k0 = kbeg + 64; k0 < kend; k0 += 64) {
    PV_STAGE(cur ^ 1, k0);   // 8 loads in flight for next tile
    ASM_VMCNT(8);            // previous tile's 8 loads retired (all waves)
    BARRIER();
    PV_COMPUTE(cur);
    BARRIER();               // reads done before next iter overwrites buf
    cur ^= 1;
  }
  ASM_VMCNT(0);
  BARRIER();
  PV_COMPUTE(cur);

  // race-free epilogue: each K-slice owns its own 16.78MB partial buffer
  float* E = part + (size_t)ks * BB * TT * DD + (size_t)b * TT * DD;
#pragma unroll
  for (int i = 0; i < 4; ++i)
#pragma unroll
    for (int j = 0; j < 4; ++j)
#pragma unroll
      for (int r = 0; r < 4; ++r) {
        const int row = m0 + wm + i * 16 + quad * 4 + r;
        const int col = n0 + wn + j * 16 + l16;
        E[(size_t)row * DD + col] = acc[i][j][r];
      }
}

// --- reduce: expected = sum of 2 split-K partials (vectorized) --------------
__global__ __launch_bounds__(256) void reduce_kernel(const float* __restrict__ part,
                                                     float* __restrict__ e) {
  const size_t idx = ((size_t)blockIdx.x * 256 + threadIdx.x) * 4;
  const size_t N = (size_t)BB * TT * DD;
  f32x4 a0 = *(const f32x4*)(part + idx);
  f32x4 a1 = *(const f32x4*)(part + N + idx);
  f32x4 o;
  o.x = a0.x + a1.x;
  o.y = a0.y + a1.y;
  o.z = a0.z + a1.z;
  o.w = a0.w + a1.w;
  *(f32x4*)(e + idx) = o;
}

// ===========================================================================
// FALLBACK PATH (R4 kernels, used when ws_size < WS_NEED)
// ===========================================================================
__global__ __launch_bounds__(256) void qk_kernel(const float* __restrict__ q,
                                                 const float* __restrict__ c,
                                                 float* __restrict__ p) {
  const int b  = blockIdx.z;
  const int m0 = blockIdx.y * 128;
  const int n0 = blockIdx.x * 128;
  const float* A  = q + (size_t)b * TT * DD;
  const float* Bt = c + (size_t)b * SS * DD;
  __shared__ alignas(16) short As[128 * 40];
  __shared__ alignas(16) short Bs[128 * 40];
  const int tid  = threadIdx.x;
  const int wave = tid >> 6, lane = tid & 63;
  const int quad = lane >> 4, l16 = lane & 15;
  const int wm = (wave >> 1) * 64, wn = (wave & 1) * 64;
  f32x4 acc[4][4];
#pragma unroll
  for (int i = 0; i < 4; ++i)
#pragma unroll
    for (int j = 0; j < 4; ++j) acc[i][j] = (f32x4){0.f, 0.f, 0.f, 0.f};
  const int ar = tid >> 1;
  const int ak = (tid & 1) * 16;
  for (int k0 = 0; k0 < DD; k0 += 32) {
    __syncthreads();
    pack16(A  + (size_t)(m0 + ar) * DD + k0 + ak, &As[ar * 40 + ak]);
    pack16(Bt + (size_t)(n0 + ar) * DD + k0 + ak, &Bs[ar * 40 + ak]);
    __syncthreads();
    bf16x8 af[4], bfv[4];
#pragma unroll
  for (int i = 0; i < 4; ++i)
      af[i] = *(const bf16x8*)&As[(wm + i * 16 + l16) * 40 + quad * 8];
#pragma unroll
    for (int j = 0; j < 4; ++j)
      bfv[j] = *(const bf16x8*)&Bs[(wn + j * 16 + l16) * 40 + quad * 8];
#pragma unroll
    for (int i = 0; i < 4; ++i)
#pragma unroll
      for (int j = 0; j < 4; ++j)
        acc[i][j] = __builtin_amdgcn_mfma_f32_16x16x32_bf16(af[i], bfv[j],
                                                            acc[i][j], 0, 0, 0);
  }
  float* P = p + (size_t)b * TT * SS;
#pragma unroll
  for (int i = 0; i < 4; ++i)
#pragma unroll
    for (int j = 0; j < 4; ++j)
#pragma unroll
      for (int r = 0; r < 4; ++r) {
        const int row = m0 + wm + i * 16 + quad * 4 + r;
        const int col = n0 + wn + j * 16 + l16;
        P[(size_t)row * SS + col] = acc[i][j][r] * 0.03125f;
      }
}

__global__ __launch_bounds__(256) void softmax_kernel(float* __restrict__ p,
                                                      const int* __restrict__ mask) {
  const int row = blockIdx.x;
  const int b   = row >> 9;
  float* pr = p + (size_t)row * SS;
  const int* mr = mask + b * SS;
  const int tid = threadIdx.x;
  const int wave = tid >> 6, lane = tid & 63;
  float v[16];
  float mx = -3.0e38f;
#pragma unroll
  for (int h = 0; h < 4; ++h) {
    const int base = tid * 4 + h * 1024;
    f32x4 s = *(const f32x4*)(pr + base);
    const int4 m4 = *(const int4*)(mr + base);
#pragma unroll
    for (int j = 0; j < 4; ++j) {
      float f = (j == 0 ? s.x : j == 1 ? s.y : j == 2 ? s.z : s.w);
      const int mk = (j == 0 ? m4.x : j == 1 ? m4.y : j == 2 ? m4.z : m4.w);
      f = fminf(fmaxf(f, -1.0e30f), 1.0e30f);
      f = (mk == 0) ? -10000.0f : f;
      v[h * 4 + j] = f;
      mx = fmaxf(mx, f);
    }
  }
#pragma unroll
  for (int off = 32; off > 0; off >>= 1) mx = fmaxf(mx, __shfl_down(mx, off));
  __shared__ float red[4];
  if (lane == 0) red[wave] = mx;
  __syncthreads();
  mx = fmaxf(fmaxf(red[0], red[1]), fmaxf(red[2], red[3]));
  __syncthreads();
  float e[16];
  float sum = 0.f;
#pragma unroll
  for (int k = 0; k < 16; ++k) { e[k] = __expf(v[k] - mx); sum += e[k]; }
#pragma unroll
  for (int off = 32; off > 0; off >>= 1) sum += __shfl_down(sum, off);
  if (lane == 0) red[wave] = sum;
  __syncthreads();
  const float inv = 1.0f / (red[0] + red[1] + red[2] + red[3]);
#pragma unroll
  for (int h = 0; h < 4; ++h) {
    const int base = tid * 4 + h * 1024;
    f32x4 o;
    o.x = e[h * 4 + 0] * inv; o.y = e[h * 4 + 1] * inv;
    o.z = e[h * 4 + 2] * inv; o.w = e[h * 4 + 3] * inv;
    *(f32x4*)(pr + base) = o;
  }
}

__global__ __launch_bounds__(256) void pv_kernel(const float* __restrict__ p,
                                                 const float* __restrict__ c,
                                                 float* __restrict__ e) {
  const int b  = blockIdx.z;
  const int m0 = blockIdx.y * 128;
  const int n0 = blockIdx.x * 128;
  const float* A  = p + (size_t)b * TT * SS;
  const float* Bm = c + (size_t)b * SS * DD;
  __shared__ alignas(16) short As[128 * 40];
  __shared__ alignas(16) short Bs[128 * 40];
  const int tid  = threadIdx.x;
  const int wave = tid >> 6, lane = tid & 63;
  const int quad = lane >> 4, l16 = lane & 15;
  const int wm = (wave >> 1) * 64, wn = (wave & 1) * 64;
  f32x4 acc[4][4];
#pragma unroll
  for (int i = 0; i < 4; ++i)
#pragma unroll
    for (int j = 0; j < 4; ++j) acc[i][j] = (f32x4){0.f, 0.f, 0.f, 0.f};
  const int ar = tid >> 1;
  const int ak = (tid & 1) * 16;
  const int kk = tid >> 3;
  const int c0 = (tid & 7) * 16;
  for (int k0 = 0; k0 < SS; k0 += 32) {
    __syncthreads();
    pack16(A + (size_t)(m0 + ar) * SS + k0 + ak, &As[ar * 40 + ak]);
    {
      const float* bp = Bm + (size_t)(k0 + kk) * DD + n0 + c0;
#pragma unroll
      for (int h = 0; h < 4; ++h) {
        f32x4 f = *(const f32x4*)(bp + h * 4);
        Bs[(c0 + h * 4 + 0) * 40 + kk] = (short)f2bf(f.x);
        Bs[(c0 + h * 4 + 1) * 40 + kk] = (short)f2bf(f.y);
        Bs[(c0 + h * 4 + 2) * 40 + kk] = (short)f2bf(f.z);
        Bs[(c0 + h * 4 + 3) * 40 + kk] = (short)f2bf(f.w);
      }
    }
    __syncthreads();
    bf16x8 af[4], bfv[4];
#pragma unroll
    for (int i = 0; i < 4; ++i)
      af[i] = *(const bf16x8*)&As[(wm + i * 16 + l16) * 40 + quad * 8];
#pragma unroll
    for (int j = 0; j < 4; ++j)
      bfv[j] = *(const bf16x8*)&Bs[(wn + j * 16 + l16) * 40 + quad * 8];
#pragma unroll
    for (int i = 0; i < 4; ++i)
#pragma unroll
      for (int j = 0; j < 4; ++j)
        acc[i][j] = __builtin_amdgcn_mfma_f32_16x16x32_bf16(af[i], bfv[j],
                                                            acc[i][j], 0, 0, 0);
  }
  float* E = e + (size_t)b * TT * DD;
#pragma unroll
  for (int i = 0; i < 4; ++i)
#pragma unroll
    for (int j = 0; j < 4; ++j)
#pragma unroll
      for (int r = 0; r < 4; ++r) {
        const int row = m0 + wm + i * 16 + quad * 4 + r;
        const int col = n0 + wn + j * 16 + l16;
        E[(size_t)row * DD + col] = acc[i][j][r];
      }
}

// ---------------------------------------------------------------------------
extern "C" void kernel_launch(void* const* d_in, const int* in_sizes, int n_in,
                              void* d_out, int out_size, void* d_ws, size_t ws_size,
                              hipStream_t stream) {
  const float* ctx   = (const float*)d_in[0];   // [8,4096,1024] f32
  const float* query = (const float*)d_in[1];   // [8,512,1024]  f32
  const int*   mask  = (const int*)d_in[2];     // [8,4096]      int32

  float* expected = (float*)d_out;                              // [8,512,1024] f32
  float* p        = (float*)d_out + (size_t)BB * TT * DD;       // [8,512,4096] f32

  if (ws_size >= WS_NEED) {
    char* ws = (char*)d_ws;
    short* qb = (short*)(ws + OFF_QB);
    short* cb = (short*)(ws + OFF_CB);
    short* pb = (short*)(ws + OFF_PB);
    float* part = (float*)(ws + OFF_PART);

    prep_q_kernel<<<dim3((BB * TT * DD) / (256 * 16)), 256, 0, stream>>>(query, qb);
    prep_cb_kernel<<<dim3((BB * SS * DD) / (256 * 16)), 256, 0, stream>>>(ctx, cb);
    qk_kernel_f<<<dim3(SS / 128, TT / 128, BB), 256, 0, stream>>>(qb, cb, mask, p);
    softmax_kernel_f<<<dim3((BB * TT) / 4), 256, 0, stream>>>(p, pb);
    pv_kernel_f<<<dim3(DD / 128, TT / 128, BB * 2), 256, 0, stream>>>(pb, cb, part);
    reduce_kernel<<<dim3((BB * TT * DD) / (256 * 4)), 256, 0, stream>>>(part, expected);
  } else {
    // fallback: R4 proven path
    qk_kernel<<<dim3(SS / 128, TT / 128, BB), 256, 0, stream>>>(query, ctx, p);
    softmax_kernel<<<dim3(BB * TT), 256, 0, stream>>>(p, mask);
    pv_kernel<<<dim3(DD / 128, TT / 128, BB), 256, 0, stream>>>(p, ctx, expected);
  }
}

// Round 9
// 348.983 us; speedup vs baseline: 1.1442x; 1.0228x over previous
//
#include <hip/hip_runtime.h>

// Problem dims (fixed by the reference)
#define BB 8
#define SS 4096
#define TT 512
#define DD 1024

typedef __attribute__((ext_vector_type(8))) short bf16x8;   // 8 bf16 = 16B
typedef __attribute__((ext_vector_type(4))) short bf16x4;   // 4 bf16 = 8B
typedef __attribute__((ext_vector_type(4))) float f32x4;

// async global->LDS, 16B per lane; LDS dest = wave-uniform base + lane*16
#define GLOAD_LDS16(gp, lp)                                            \
  __builtin_amdgcn_global_load_lds(                                    \
      (const __attribute__((address_space(1))) void*)(gp),             \
      (__attribute__((address_space(3))) void*)(lp), 16, 0, 0)

// T4 counted-vmcnt barrier discipline (m218/m201 pattern)
#define ASM_VMCNT(n) asm volatile("s_waitcnt vmcnt(" #n ")" ::: "memory")
#define BARRIER() __builtin_amdgcn_s_barrier()

__device__ inline unsigned short f2bf(float f) {
  unsigned int u = __float_as_uint(f);
  u += 0x7FFFu + ((u >> 16) & 1u);   // round-to-nearest-even
  return (unsigned short)(u >> 16);
}
// pack 16 consecutive f32 -> two bf16x8 (16B-aligned dst)
__device__ inline void pack16(const float* __restrict__ src, short* __restrict__ dst) {
  f32x4 f0 = *(const f32x4*)(src + 0);
  f32x4 f1 = *(const f32x4*)(src + 4);
  f32x4 f2 = *(const f32x4*)(src + 8);
  f32x4 f3 = *(const f32x4*)(src + 12);
  bf16x8 b0, b1;
  b0[0] = (short)f2bf(f0.x); b0[1] = (short)f2bf(f0.y);
  b0[2] = (short)f2bf(f0.z); b0[3] = (short)f2bf(f0.w);
  b0[4] = (short)f2bf(f1.x); b0[5] = (short)f2bf(f1.y);
  b0[6] = (short)f2bf(f1.z); b0[7] = (short)f2bf(f1.w);
  b1[0] = (short)f2bf(f2.x); b1[1] = (short)f2bf(f2.y);
  b1[2] = (short)f2bf(f2.z); b1[3] = (short)f2bf(f2.w);
  b1[4] = (short)f2bf(f3.x); b1[5] = (short)f2bf(f3.y);
  b1[6] = (short)f2bf(f3.z); b1[7] = (short)f2bf(f3.w);
  *(bf16x8*)(dst + 0) = b0;
  *(bf16x8*)(dst + 8) = b1;
}

// ===========================================================================
// FAST PATH (needs 168 MB workspace)
// ws: q_bf16 [T,D] 8MB | c_bf16 [S,D] 64MB | part (2x16.78MB, old ct region)
//     | pb 32MB at 136MB.  NO ct: pv consumes cb directly via
//     ds_read_b64_tr_b16 hardware-transpose reads (T10).
// ===========================================================================
#define WS_NEED ((size_t)168 << 20)
#define OFF_QB  ((size_t)0)
#define OFF_CB  ((size_t)8 << 20)
#define OFF_PART ((size_t)72 << 20)   // old ct region (pv reads cb, so no overlap)
#define OFF_PB  ((size_t)136 << 20)

// --- prep: query f32 -> bf16 ------------------------------------------------
__global__ __launch_bounds__(256) void prep_q_kernel(const float* __restrict__ q,
                                                     short* __restrict__ qb) {
  const size_t idx = ((size_t)blockIdx.x * 256 + threadIdx.x) * 16;
  pack16(q + idx, qb + idx);
}

// --- prep: ctx f32 -> c_bf16 [S,D] (pure streaming, no LDS, no transpose) ---
__global__ __launch_bounds__(256) void prep_cb_kernel(const float* __restrict__ c,
                                                      short* __restrict__ cb) {
  const size_t idx = ((size_t)blockIdx.x * 256 + threadIdx.x) * 16;
  pack16(c + idx, cb + idx);
}

// ---------------------------------------------------------------------------
// qk: 256x256 tile, BK=64, 8 waves (2M x 4N), LDS 128KB dbuf, counted-vmcnt
// schedule (proven R7 structure, new geometry). Rationale: 128^2 was
// LDS-BW-bound (fragment reads per FLOP); 256^2 halves staging bytes/FLOP
// and cuts fragment reads/FLOP 25% (m230: 256^2+2ph = 682 TF vs 128^2 ~460).
// Chunk swizzle invariant: staging rowbase === 0 (mod 8), lane l writes row
// base+(l>>3) slot (l&7) holding global chunk (l&7)^(l>>3) -> slot s of row
// r holds chunk s^(r&7); read slot = (kk*4+quad)^(l16&7). 2-way free.
// ---------------------------------------------------------------------------
__global__ __launch_bounds__(512) void qk_kernel_f(const short* __restrict__ qb,
                                                   const short* __restrict__ cb,
                                                   const int* __restrict__ mask,
                                                   float* __restrict__ p) {
  const int b  = blockIdx.z;
  const int m0 = blockIdx.y * 256;   // T
  const int n0 = blockIdx.x * 256;   // S
  const short* A  = qb + (size_t)b * TT * DD;
  const short* Bt = cb + (size_t)b * SS * DD;

  __shared__ alignas(16) short As[2][256 * 64];   // 64 KB
  __shared__ alignas(16) short Bs[2][256 * 64];   // 64 KB

  const int tid  = threadIdx.x;
  const int wave = tid >> 6, lane = tid & 63;
  const int quad = lane >> 4, l16 = lane & 15;
  const int wm = (wave >> 2) * 128;   // 2 M-waves
  const int wn = (wave & 3) * 64;     // 4 N-waves

  const int rl = lane >> 3;                       // staging row 0..7
  const int ck = (lane & 7) ^ (lane >> 3);        // swizzled k-chunk 0..7
  const int x7 = l16 & 7;                         // read-side row&7

  f32x4 acc[8][4];
#pragma unroll
  for (int i = 0; i < 8; ++i)
#pragma unroll
    for (int j = 0; j < 4; ++j) acc[i][j] = (f32x4){0.f, 0.f, 0.f, 0.f};

#define QK_STAGE(buf, k0)                                                     \
  {                                                                           \
    _Pragma("unroll")                                                         \
    for (int t = 0; t < 4; ++t) {                                             \
      const int rb = wave * 8 + t * 64;            /* wave-uniform, %8==0 */  \
      GLOAD_LDS16(A  + (size_t)(m0 + rb + rl) * DD + (k0) + ck * 8,           \
                  &As[buf][rb * 64]);                                         \
      GLOAD_LDS16(Bt + (size_t)(n0 + rb + rl) * DD + (k0) + ck * 8,           \
                  &Bs[buf][rb * 64]);                                         \
    }                                                                         \
  }

#define QK_COMPUTE(buf)                                                       \
  {                                                                           \
    _Pragma("unroll")                                                         \
    for (int kk = 0; kk < 2; ++kk) {                                          \
      const int slot = ((kk * 4 + quad) ^ x7) * 8;                            \
      bf16x8 af[8], bfv[4];                                                   \
      _Pragma("unroll")                                                       \
      for (int i = 0; i < 8; ++i)                                             \
        af[i] = *(const bf16x8*)&As[buf][(wm + i * 16 + l16) * 64 + slot];    \
      _Pragma("unroll")                                                       \
      for (int j = 0; j < 4; ++j)                                             \
        bfv[j] = *(const bf16x8*)&Bs[buf][(wn + j * 16 + l16) * 64 + slot];   \
      _Pragma("unroll")                                                       \
      for (int i = 0; i < 8; ++i)                                             \
        _Pragma("unroll")                                                     \
        for (int j = 0; j < 4; ++j)                                           \
          acc[i][j] = __builtin_amdgcn_mfma_f32_16x16x32_bf16(                \
              af[i], bfv[j], acc[i][j], 0, 0, 0);                             \
    }                                                                         \
  }

  QK_STAGE(0, 0);
  int cur = 0;
  for (int k0 = 64; k0 < DD; k0 += 64) {
    QK_STAGE(cur ^ 1, k0);   // 8 loads in flight for next tile
    ASM_VMCNT(8);            // previous tile's 8 loads retired (all waves)
    BARRIER();
    QK_COMPUTE(cur);
    BARRIER();               // reads done before next iter overwrites buf
    cur ^= 1;
  }
  ASM_VMCNT(0);
  BARRIER();
  QK_COMPUTE(cur);

  // epilogue: scale + mask (masked cols -> -10000; softmax needs no mask)
  float* P = p + (size_t)b * TT * SS;
  int mk[4];
#pragma unroll
  for (int j = 0; j < 4; ++j) mk[j] = mask[b * SS + n0 + wn + j * 16 + l16];
#pragma unroll
  for (int i = 0; i < 8; ++i)
#pragma unroll
    for (int j = 0; j < 4; ++j)
#pragma unroll
      for (int r = 0; r < 4; ++r) {
        const int row = m0 + wm + i * 16 + quad * 4 + r;
        const int col = n0 + wn + j * 16 + l16;
        const float val = (mk[j] == 0) ? -10000.0f : acc[i][j][r] * 0.03125f;
        P[(size_t)row * SS + col] = val;
      }
}

// --- softmax: wave-per-row, zero barriers, zero LDS -------------------------
__global__ __launch_bounds__(256) void softmax_kernel_f(float* __restrict__ p,
                                                        short* __restrict__ pb) {
  const int wave = threadIdx.x >> 6, lane = threadIdx.x & 63;
  const int row = blockIdx.x * 4 + wave;        // b*T + t
  float* pr = p + (size_t)row * SS;
  short* pbr = pb + (size_t)row * SS;

  f32x4 v[16];
  float mx = -3.0e38f;
#pragma unroll
  for (int h = 0; h < 16; ++h) {
    v[h] = *(const f32x4*)(pr + h * 256 + lane * 4);
    mx = fmaxf(mx, fmaxf(fmaxf(v[h].x, v[h].y), fmaxf(v[h].z, v[h].w)));
  }
#pragma unroll
  for (int off = 32; off > 0; off >>= 1) mx = fmaxf(mx, __shfl_xor(mx, off));

  float sum = 0.f;
#pragma unroll
  for (int h = 0; h < 16; ++h) {
    v[h].x = __expf(v[h].x - mx);
    v[h].y = __expf(v[h].y - mx);
    v[h].z = __expf(v[h].z - mx);
    v[h].w = __expf(v[h].w - mx);
    sum += (v[h].x + v[h].y) + (v[h].z + v[h].w);
  }
#pragma unroll
  for (int off = 32; off > 0; off >>= 1) sum += __shfl_xor(sum, off);
  const float inv = 1.0f / sum;

#pragma unroll
  for (int h = 0; h < 16; ++h) {
    f32x4 o;
    o.x = v[h].x * inv; o.y = v[h].y * inv;
    o.z = v[h].z * inv; o.w = v[h].w * inv;
    *(f32x4*)(pr + h * 256 + lane * 4) = o;
    bf16x4 ob;
    ob[0] = (short)f2bf(o.x); ob[1] = (short)f2bf(o.y);
    ob[2] = (short)f2bf(o.z); ob[3] = (short)f2bf(o.w);
    *(bf16x4*)(pbr + h * 256 + lane * 4) = ob;
  }
}

// --- pv: A from pb; B from cb rows via subtiled LDS + tr-reads (T10) --------
__global__ __launch_bounds__(256) void pv_kernel_f(const short* __restrict__ pb,
                                                   const short* __restrict__ cb,
                                                   float* __restrict__ part) {
  const int n0 = blockIdx.x * 128;   // D
  const int m0 = blockIdx.y * 128;   // T
  const int z  = blockIdx.z;
  const int b  = z >> 1;
  const int ks = z & 1;              // K slice: s in [ks*2048, +2048)
  const short* A   = pb + (size_t)b * TT * SS;
  const short* Vrm = cb + (size_t)b * SS * DD;   // V row-major [s][d]

  __shared__ alignas(16) short As[2][128 * 64];
  __shared__ alignas(16) short Bs[2][64 * 128];  // subtiled [16][8][4][16]

  const int tid  = threadIdx.x;
  const int wave = tid >> 6, lane = tid & 63;
  const int quad = lane >> 4, l16 = lane & 15;
  const int wm = (wave >> 1) * 64, wn = (wave & 1) * 64;

  const int rl = lane >> 3;                 // A staging row 0..7
  const int ck = (lane & 7) ^ (lane >> 3);  // A swizzled k-chunk
  const int x7 = l16 & 7;

  // B staging source decomposition (dest = linear lane*16 in subtiled layout)
  const int rB  = (lane & 7) >> 1;          // k within rowblock 0..3
  const int dB  = (lane >> 3) * 16 + (lane & 1) * 8;   // d offset 0..120

  // B tr-read per-lane base (bytes into LDS)
  const unsigned ldsB0 = (unsigned)(unsigned long long)&Bs[0][0];
  const unsigned baseBq = ldsB0 + (unsigned)(quad * 2048 + (wave & 1) * 512 + l16 * 8);

  f32x4 acc[4][4];
#pragma unroll
  for (int i = 0; i < 4; ++i)
#pragma unroll
    for (int j = 0; j < 4; ++j) acc[i][j] = (f32x4){0.f, 0.f, 0.f, 0.f};

#define PV_STAGE(buf, k0)                                                     \
  {                                                                           \
    _Pragma("unroll")                                                         \
    for (int t = 0; t < 4; ++t) {                                             \
      const int rb = wave * 32 + t * 8;                                       \
      GLOAD_LDS16(A + (size_t)(m0 + rb + rl) * SS + (k0) + ck * 8,            \
                  &As[buf][rb * 64]);                                         \
      const int kg = wave * 4 + t;          /* rowblock 0..15 */              \
      GLOAD_LDS16(Vrm + (size_t)((k0) + kg * 4 + rB) * DD + n0 + dB,          \
                  &Bs[buf][kg * 512]);                                        \
    }                                                                         \
  }

#define PV_COMPUTE(buf)                                                       \
  {                                                                           \
    const unsigned bb = baseBq + (unsigned)(buf) * 16384u;                    \
    _Pragma("unroll")                                                         \
    for (int kk = 0; kk < 2; ++kk) {                                          \
      bf16x8 af[4];                                                           \
      _Pragma("unroll")                                                       \
      for (int i = 0; i < 4; ++i)                                             \
        af[i] = *(const bf16x8*)&As[buf][(wm + i * 16 + l16) * 64 +           \
                                        (((kk * 4 + quad) ^ x7) * 8)];        \
      union { struct { int2 lo, hi; } p; bf16x8 v; } bu[4];                   \
      _Pragma("unroll")                                                       \
      for (int j = 0; j < 4; ++j) {                                           \
        const unsigned aj = bb + (unsigned)(kk * 8192 + j * 128);             \
        asm volatile("ds_read_b64_tr_b16 %0, %1"                              \
                     : "=v"(bu[j].p.lo) : "v"(aj) : "memory");                \
        asm volatile("ds_read_b64_tr_b16 %0, %1 offset:1024"                  \
                     : "=v"(bu[j].p.hi) : "v"(aj) : "memory");                \
      }                                                                       \
      asm volatile("s_waitcnt lgkmcnt(0)" ::: "memory");                      \
      __builtin_amdgcn_sched_barrier(0);                                      \
      _Pragma("unroll")                                                       \
      for (int i = 0; i < 4; ++i)                                             \
        _Pragma("unroll")                                                     \
        for (int j = 0; j < 4; ++j)                                           \
          acc[i][j] = __builtin_amdgcn_mfma_f32_16x16x32_bf16(                \
              af[i], bu[j].v, acc[i][j], 0, 0, 0);                            \
    }                                                                         \
  }

  const int kbeg = ks * 2048;
  const int kend = kbeg + 2048;
  PV_STAGE(0, kbeg);
  int cur = 0;
  for (int k0 = kbeg + 64; k0 < kend; k0 += 64) {
    PV_STAGE(cur ^ 1, k0);   // 8 loads in flight for next tile
    ASM_VMCNT(8);            // previous tile's 8 loads retired (all waves)
    BARRIER();
    PV_COMPUTE(cur);
    BARRIER();               // reads done before next iter overwrites buf
    cur ^= 1;
  }
  ASM_VMCNT(0);
  BARRIER();
  PV_COMPUTE(cur);

  // race-free epilogue: each K-slice owns its own 16.78MB partial buffer
  float* E = part + (size_t)ks * BB * TT * DD + (size_t)b * TT * DD;
#pragma unroll
  for (int i = 0; i < 4; ++i)
#pragma unroll
    for (int j = 0; j < 4; ++j)
#pragma unroll
      for (int r = 0; r < 4; ++r) {
        const int row = m0 + wm + i * 16 + quad * 4 + r;
        const int col = n0 + wn + j * 16 + l16;
        E[(size_t)row * DD + col] = acc[i][j][r];
      }
}

// --- reduce: expected = sum of 2 split-K partials (vectorized) --------------
__global__ __launch_bounds__(256) void reduce_kernel(const float* __restrict__ part,
                                                     float* __restrict__ e) {
  const size_t idx = ((size_t)blockIdx.x * 256 + threadIdx.x) * 4;
  const size_t N = (size_t)BB * TT * DD;
  f32x4 a0 = *(const f32x4*)(part + idx);
  f32x4 a1 = *(const f32x4*)(part + N + idx);
  f32x4 o;
  o.x = a0.x + a1.x;
  o.y = a0.y + a1.y;
  o.z = a0.z + a1.z;
  o.w = a0.w + a1.w;
  *(f32x4*)(e + idx) = o;
}

// ===========================================================================
// FALLBACK PATH (R4 kernels, used when ws_size < WS_NEED)
// ===========================================================================
__global__ __launch_bounds__(256) void qk_kernel(const float* __restrict__ q,
                                                 const float* __restrict__ c,
                                                 float* __restrict__ p) {
  const int b  = blockIdx.z;
  const int m0 = blockIdx.y * 128;
  const int n0 = blockIdx.x * 128;
  const float* A  = q + (size_t)b * TT * DD;
  const float* Bt = c + (size_t)b * SS * DD;
  __shared__ alignas(16) short As[128 * 40];
  __shared__ alignas(16) short Bs[128 * 40];
  const int tid  = threadIdx.x;
  const int wave = tid >> 6, lane = tid & 63;
  const int quad = lane >> 4, l16 = lane & 15;
  const int wm = (wave >> 1) * 64, wn = (wave & 1) * 64;
  f32x4 acc[4][4];
#pragma unroll
  for (int i = 0; i < 4; ++i)
#pragma unroll
    for (int j = 0; j < 4; ++j) acc[i][j] = (f32x4){0.f, 0.f, 0.f, 0.f};
  const int ar = tid >> 1;
  const int ak = (tid & 1) * 16;
  for (int k0 = 0; k0 < DD; k0 += 32) {
    __syncthreads();
    pack16(A  + (size_t)(m0 + ar) * DD + k0 + ak, &As[ar * 40 + ak]);
    pack16(Bt + (size_t)(n0 + ar) * DD + k0 + ak, &Bs[ar * 40 + ak]);
    __syncthreads();
    bf16x8 af[4], bfv[4];
#pragma unroll
  for (int i = 0; i < 4; ++i)
      af[i] = *(const bf16x8*)&As[(wm + i * 16 + l16) * 40 + quad * 8];
#pragma unroll
    for (int j = 0; j < 4; ++j)
      bfv[j] = *(const bf16x8*)&Bs[(wn + j * 16 + l16) * 40 + quad * 8];
#pragma unroll
    for (int i = 0; i < 4; ++i)
#pragma unroll
      for (int j = 0; j < 4; ++j)
        acc[i][j] = __builtin_amdgcn_mfma_f32_16x16x32_bf16(af[i], bfv[j],
                                                            acc[i][j], 0, 0, 0);
  }
  float* P = p + (size_t)b * TT * SS;
#pragma unroll
  for (int i = 0; i < 4; ++i)
#pragma unroll
    for (int j = 0; j < 4; ++j)
#pragma unroll
      for (int r = 0; r < 4; ++r) {
        const int row = m0 + wm + i * 16 + quad * 4 + r;
        const int col = n0 + wn + j * 16 + l16;
        P[(size_t)row * SS + col] = acc[i][j][r] * 0.03125f;
      }
}

__global__ __launch_bounds__(256) void softmax_kernel(float* __restrict__ p,
                                                      const int* __restrict__ mask) {
  const int row = blockIdx.x;
  const int b   = row >> 9;
  float* pr = p + (size_t)row * SS;
  const int* mr = mask + b * SS;
  const int tid = threadIdx.x;
  const int wave = tid >> 6, lane = tid & 63;
  float v[16];
  float mx = -3.0e38f;
#pragma unroll
  for (int h = 0; h < 4; ++h) {
    const int base = tid * 4 + h * 1024;
    f32x4 s = *(const f32x4*)(pr + base);
    const int4 m4 = *(const int4*)(mr + base);
#pragma unroll
    for (int j = 0; j < 4; ++j) {
      float f = (j == 0 ? s.x : j == 1 ? s.y : j == 2 ? s.z : s.w);
      const int mk = (j == 0 ? m4.x : j == 1 ? m4.y : j == 2 ? m4.z : m4.w);
      f = fminf(fmaxf(f, -1.0e30f), 1.0e30f);
      f = (mk == 0) ? -10000.0f : f;
      v[h * 4 + j] = f;
      mx = fmaxf(mx, f);
    }
  }
#pragma unroll
  for (int off = 32; off > 0; off >>= 1) mx = fmaxf(mx, __shfl_down(mx, off));
  __shared__ float red[4];
  if (lane == 0) red[wave] = mx;
  __syncthreads();
  mx = fmaxf(fmaxf(red[0], red[1]), fmaxf(red[2], red[3]));
  __syncthreads();
  float e[16];
  float sum = 0.f;
#pragma unroll
  for (int k = 0; k < 16; ++k) { e[k] = __expf(v[k] - mx); sum += e[k]; }
#pragma unroll
  for (int off = 32; off > 0; off >>= 1) sum += __shfl_down(sum, off);
  if (lane == 0) red[wave] = sum;
  __syncthreads();
  const float inv = 1.0f / (red[0] + red[1] + red[2] + red[3]);
#pragma unroll
  for (int h = 0; h < 4; ++h) {
    const int base = tid * 4 + h * 1024;
    f32x4 o;
    o.x = e[h * 4 + 0] * inv; o.y = e[h * 4 + 1] * inv;
    o.z = e[h * 4 + 2] * inv; o.w = e[h * 4 + 3] * inv;
    *(f32x4*)(pr + base) = o;
  }
}

__global__ __launch_bounds__(256) void pv_kernel(const float* __restrict__ p,
                                                 const float* __restrict__ c,
                                                 float* __restrict__ e) {
  const int b  = blockIdx.z;
  const int m0 = blockIdx.y * 128;
  const int n0 = blockIdx.x * 128;
  const float* A  = p + (size_t)b * TT * SS;
  const float* Bm = c + (size_t)b * SS * DD;
  __shared__ alignas(16) short As[128 * 40];
  __shared__ alignas(16) short Bs[128 * 40];
  const int tid  = threadIdx.x;
  const int wave = tid >> 6, lane = tid & 63;
  const int quad = lane >> 4, l16 = lane & 15;
  const int wm = (wave >> 1) * 64, wn = (wave & 1) * 64;
  f32x4 acc[4][4];
#pragma unroll
  for (int i = 0; i < 4; ++i)
#pragma unroll
    for (int j = 0; j < 4; ++j) acc[i][j] = (f32x4){0.f, 0.f, 0.f, 0.f};
  const int ar = tid >> 1;
  const int ak = (tid & 1) * 16;
  const int kk = tid >> 3;
  const int c0 = (tid & 7) * 16;
  for (int k0 = 0; k0 < SS; k0 += 32) {
    __syncthreads();
    pack16(A + (size_t)(m0 + ar) * SS + k0 + ak, &As[ar * 40 + ak]);
    {
      const float* bp = Bm + (size_t)(k0 + kk) * DD + n0 + c0;
#pragma unroll
      for (int h = 0; h < 4; ++h) {
        f32x4 f = *(const f32x4*)(bp + h * 4);
        Bs[(c0 + h * 4 + 0) * 40 + kk] = (short)f2bf(f.x);
        Bs[(c0 + h * 4 + 1) * 40 + kk] = (short)f2bf(f.y);
        Bs[(c0 + h * 4 + 2) * 40 + kk] = (short)f2bf(f.z);
        Bs[(c0 + h * 4 + 3) * 40 + kk] = (short)f2bf(f.w);
      }
    }
    __syncthreads();
    bf16x8 af[4], bfv[4];
#pragma unroll
    for (int i = 0; i < 4; ++i)
      af[i] = *(const bf16x8*)&As[(wm + i * 16 + l16) * 40 + quad * 8];
#pragma unroll
    for (int j = 0; j < 4; ++j)
      bfv[j] = *(const bf16x8*)&Bs[(wn + j * 16 + l16) * 40 + quad * 8];
#pragma unroll
    for (int i = 0; i < 4; ++i)
#pragma unroll
      for (int j = 0; j < 4; ++j)
        acc[i][j] = __builtin_amdgcn_mfma_f32_16x16x32_bf16(af[i], bfv[j],
                                                            acc[i][j], 0, 0, 0);
  }
  float* E = e + (size_t)b * TT * DD;
#pragma unroll
  for (int i = 0; i < 4; ++i)
#pragma unroll
    for (int j = 0; j < 4; ++j)
#pragma unroll
      for (int r = 0; r < 4; ++r) {
        const int row = m0 + wm + i * 16 + quad * 4 + r;
        const int col = n0 + wn + j * 16 + l16;
        E[(size_t)row * DD + col] = acc[i][j][r];
      }
}

// ---------------------------------------------------------------------------
extern "C" void kernel_launch(void* const* d_in, const int* in_sizes, int n_in,
                              void* d_out, int out_size, void* d_ws, size_t ws_size,
                              hipStream_t stream) {
  const float* ctx   = (const float*)d_in[0];   // [8,4096,1024] f32
  const float* query = (const float*)d_in[1];   // [8,512,1024]  f32
  const int*   mask  = (const int*)d_in[2];     // [8,4096]      int32

  float* expected = (float*)d_out;                              // [8,512,1024] f32
  float* p        = (float*)d_out + (size_t)BB * TT * DD;       // [8,512,4096] f32

  if (ws_size >= WS_NEED) {
    char* ws = (char*)d_ws;
    short* qb = (short*)(ws + OFF_QB);
    short* cb = (short*)(ws + OFF_CB);
    short* pb = (short*)(ws + OFF_PB);
    float* part = (float*)(ws + OFF_PART);

    prep_q_kernel<<<dim3((BB * TT * DD) / (256 * 16)), 256, 0, stream>>>(query, qb);
    prep_cb_kernel<<<dim3((BB * SS * DD) / (256 * 16)), 256, 0, stream>>>(ctx, cb);
    qk_kernel_f<<<dim3(SS / 256, TT / 256, BB), 512, 0, stream>>>(qb, cb, mask, p);
    softmax_kernel_f<<<dim3((BB * TT) / 4), 256, 0, stream>>>(p, pb);
    pv_kernel_f<<<dim3(DD / 128, TT / 128, BB * 2), 256, 0, stream>>>(pb, cb, part);
    reduce_kernel<<<dim3((BB * TT * DD) / (256 * 4)), 256, 0, stream>>>(part, expected);
  } else {
    // fallback: R4 proven path
    qk_kernel<<<dim3(SS / 128, TT / 128, BB), 256, 0, stream>>>(query, ctx, p);
    softmax_kernel<<<dim3(BB * TT), 256, 0, stream>>>(p, mask);
    pv_kernel<<<dim3(DD / 128, TT / 128, BB), 256, 0, stream>>>(p, ctx, expected);
  }
}